// Round 8
// baseline (361.746 us; speedup 1.0000x reference)
//
#include <hip/hip_runtime.h>

#define B_ 2
#define C_ 256
#define N_ 8192
#define NG_ 32

typedef unsigned int u32;
using f32x4  = __attribute__((ext_vector_type(4))) float;
using f32x16 = __attribute__((ext_vector_type(16))) float;
using s8v    = __attribute__((ext_vector_type(8))) short;   // 8 x bf16
using u32x2  = __attribute__((ext_vector_type(2))) u32;

__device__ __forceinline__ unsigned short f2bf(float f) {
  unsigned u = __builtin_bit_cast(unsigned, f);
  return (unsigned short)((u + 0x7fffu + ((u >> 16) & 1u)) >> 16);
}
__device__ __forceinline__ float bf2f(unsigned short h) {
  return __builtin_bit_cast(float, (u32)h << 16);
}
// pack two f32 -> two bf16 (RTNE) in one instr
__device__ __forceinline__ u32 cvtpk(float lo, float hi) {
  u32 r;
  asm volatile("v_cvt_pk_bf16_f32 %0, %1, %2" : "=v"(r) : "v"(lo), "v"(hi));
  return r;
}
// v_permlane32_swap_b32 a, b:  newA = [a.row0, b.row0], newB = [a.row1, b.row1]
__device__ __forceinline__ void swap32u(u32& a, u32& b) {
  asm volatile("v_permlane32_swap_b32 %0, %1" : "+v"(a), "+v"(b));
}
__device__ __forceinline__ float xhalf_max(float x) {
  float a = x, b = x;
  asm volatile("v_permlane32_swap_b32 %0, %1" : "+v"(a), "+v"(b));
  return fmaxf(a, b);        // max(own-half, other-half) on every lane
}
__device__ __forceinline__ float xhalf_sum(float x) {
  float a = x, b = x;
  asm volatile("v_permlane32_swap_b32 %0, %1" : "+v"(a), "+v"(b));
  return a + b;
}

// ---------------- weight fp32 -> bf16 (4 x 256x256, contiguous out) ---------
__global__ void cvt_w_kernel(const float* __restrict__ wq, const float* __restrict__ wk,
                             const float* __restrict__ wv, const float* __restrict__ wp,
                             unsigned short* __restrict__ out) {
  int i = blockIdx.x * 256 + threadIdx.x;        // 262144 total
  int m = i >> 16;
  const float* src = m == 0 ? wq : m == 1 ? wk : m == 2 ? wv : wp;
  out[i] = f2bf(src[i & 65535]);
}

// ---------------- groupnorm pass 1: mean/rstd per (b, group) ----------------
__global__ void gn_stats_kernel(const float* __restrict__ x,
                                float* __restrict__ mean, float* __restrict__ rstd) {
  int bg = blockIdx.x;                                  // 64 groups total
  const f32x4* p = (const f32x4*)(x + (size_t)bg * (8 * N_));
  float s = 0.f, sq = 0.f;
  for (int i = threadIdx.x; i < 8 * N_ / 4; i += 256) {
    f32x4 v = p[i];
    s  += v.x + v.y + v.z + v.w;
    sq += v.x * v.x + v.y * v.y + v.z * v.z + v.w * v.w;
  }
  #pragma unroll
  for (int o = 32; o; o >>= 1) { s += __shfl_down(s, o); sq += __shfl_down(sq, o); }
  __shared__ float ls[4], lq[4];
  int w = threadIdx.x >> 6;
  if ((threadIdx.x & 63) == 0) { ls[w] = s; lq[w] = sq; }
  __syncthreads();
  if (threadIdx.x == 0) {
    s = ls[0] + ls[1] + ls[2] + ls[3];
    sq = lq[0] + lq[1] + lq[2] + lq[3];
    float m = s / (8.f * N_);
    float var = sq / (8.f * N_) - m * m;
    mean[bg] = m;
    rstd[bg] = rsqrtf(var + 1e-5f);
  }
}

// -------- groupnorm pass 2: normalize + transpose -> h[N][C] bf16 -----------
__global__ __launch_bounds__(256) void gn_apply_kernel(
    const float* __restrict__ x, const float* __restrict__ gw, const float* __restrict__ gb,
    const float* __restrict__ mean, const float* __restrict__ rstd,
    unsigned short* __restrict__ h) {
  __shared__ unsigned short lds[256][72];
  int b = blockIdx.y, n0 = blockIdx.x * 64;
  const float* xb = x + (size_t)b * C_ * N_;
  int col = threadIdx.x & 63;
  int c0  = threadIdx.x >> 6;
  for (int r = 0; r < 64; ++r) {
    int c = r * 4 + c0;
    float v = xb[(size_t)c * N_ + n0 + col];
    int g = b * NG_ + (c >> 3);
    lds[c][col] = f2bf((v - mean[g]) * rstd[g] * gw[c] + gb[c]);
  }
  __syncthreads();
  int nl = threadIdx.x >> 2;                      // 0..63
  int cb = threadIdx.x & 3;                       // 0..3 (64-channel chunk)
  unsigned short* dst = h + ((size_t)b * N_ + n0 + nl) * C_ + cb * 64;
  #pragma unroll
  for (int g2 = 0; g2 < 8; ++g2) {
    s8v v;
    #pragma unroll
    for (int e = 0; e < 8; ++e) v[e] = (short)lds[cb * 64 + g2 * 8 + e][nl];
    *(s8v*)(dst + g2 * 8) = v;
  }
}

// -------- generic C[i][j] = sum_k A[i][k]*B[j][k] (bf16 in, K=256) ----------
template <int MODE>
__global__ __launch_bounds__(256) void gemm_nt_kernel(
    const unsigned short* __restrict__ A, long sA,
    const unsigned short* __restrict__ Bm, long sB,
    const float* __restrict__ bias,
    const float* __restrict__ resid, long sR,
    void* __restrict__ outv, long sO, int ldo) {
  int b = blockIdx.z;
  const unsigned short* Ab = A + (size_t)b * sA;
  const unsigned short* Bb = Bm + (size_t)b * sB;
  int i0 = blockIdx.x * 64, j0 = blockIdx.y * 64;
  int lane = threadIdx.x & 63, w = threadIdx.x >> 6;
  int l15 = lane & 15, lg = lane >> 4;
  const unsigned short* Ap = Ab + (size_t)(i0 + w * 16 + l15) * 256 + lg * 8;
  const unsigned short* Bp = Bb + (size_t)(j0 + l15) * 256 + lg * 8;
  f32x4 acc[4];
  #pragma unroll
  for (int jt = 0; jt < 4; ++jt) acc[jt] = f32x4{0.f, 0.f, 0.f, 0.f};
  #pragma unroll
  for (int kt = 0; kt < 8; ++kt) {
    s8v a = *(const s8v*)(Ap + kt * 32);
    #pragma unroll
    for (int jt = 0; jt < 4; ++jt) {
      s8v bb = *(const s8v*)(Bp + (size_t)jt * 16 * 256 + kt * 32);
      acc[jt] = __builtin_amdgcn_mfma_f32_16x16x32_bf16(a, bb, acc[jt], 0, 0, 0);
    }
  }
  int rowb = i0 + w * 16 + lg * 4;
  if (MODE == 0) {
    unsigned short* o = (unsigned short*)outv + (size_t)b * sO;
    #pragma unroll
    for (int jt = 0; jt < 4; ++jt) {
      int j = j0 + jt * 16 + l15;
      float bj = bias[j];
      #pragma unroll
      for (int r = 0; r < 4; ++r)
        o[(size_t)(rowb + r) * ldo + j] = f2bf(acc[jt][r] + bj);
    }
  } else if (MODE == 1) {
    unsigned short* o = (unsigned short*)outv + (size_t)b * sO;
    #pragma unroll
    for (int jt = 0; jt < 4; ++jt) {
      int j = j0 + jt * 16 + l15;
      #pragma unroll
      for (int r = 0; r < 4; ++r)
        o[(size_t)(rowb + r) * ldo + j] = f2bf(acc[jt][r] + bias[rowb + r]);
    }
  } else {
    float* o = (float*)outv + (size_t)b * sO;
    const float* xr = resid + (size_t)b * sR;
    #pragma unroll
    for (int jt = 0; jt < 4; ++jt) {
      int j = j0 + jt * 16 + l15;
      #pragma unroll
      for (int r = 0; r < 4; ++r) {
        size_t idx = (size_t)(rowb + r) * ldo + j;
        o[idx] = acc[jt][r] + bias[rowb + r] + xr[idx];
      }
    }
  }
}

// ---------------- flash attention pass 1 (swapped-QK^T, T15 pipeline) -------
// 256 thr = 4 waves, 32 q-rows/wave (QBLK=128). KVBLK=32, 4 KV slices.
// Two-tile software pipeline: QK(it+1) -> sa_next interleaves (same BB,
// branchless softmax) with softmax(it)+PV(it). K lead-2 staged, tile parity
// == buffer parity; V lead-1; ONE barrier per iteration.
// Cross-half ops via v_permlane32_swap; P pack via v_cvt_pk_bf16_f32.
// LDS: K 2x16KB + V 2x16KB = 65536 B. 2 blocks/CU, 2 waves/SIMD (reg-capped).
__global__ __launch_bounds__(256, 2) void attn_kernel(
    const unsigned short* __restrict__ Q, const unsigned short* __restrict__ K,
    const unsigned short* __restrict__ V, unsigned short* __restrict__ Op,
    float* __restrict__ lse) {
  extern __shared__ unsigned short smem[];
  // dispatch remap: 8 consecutive blockIdx -> 8 XCDs; each XCD's resident set
  // shares one (sl,b) so its 2MB K/V slice lives in its 4MB L2.
  int f = blockIdx.x;
  int grp = f & 7, qb = f >> 3;
  int sl = grp & 3, b = grp >> 2;
  int q0 = qb * 128;
  int kvbase = sl * 2048;
  int t = threadIdx.x, lane = t & 63, w = t >> 6;
  int l31 = lane & 31, hi = lane >> 5;

  const unsigned short* Qg = Q + ((size_t)b * N_ + q0 + w * 32 + l31) * 256;
  const unsigned short* Kg = K + ((size_t)b * N_ + kvbase) * 256;
  const unsigned short* Vg = V + (size_t)b * 256 * N_ + kvbase;
  const float sc = 0.0625f * 1.44269504088896f;          // C^-0.5 * log2(e)

  // Q as B-operand frags: col(q)=lane&31, k = hi*8+e ; 16 k-slots of 16
  s8v qf[16];
  #pragma unroll
  for (int tt = 0; tt < 16; ++tt)
    qf[tt] = *(const s8v*)(Qg + tt * 16 + hi * 8);

  f32x16 o_acc[8];                                       // O^T: d-chunk x 16
  #pragma unroll
  for (int dc = 0; dc < 8; ++dc)
    #pragma unroll
    for (int r = 0; r < 16; ++r) o_acc[dc][r] = 0.f;
  float m_r = -1e30f, l_r = 0.f;                          // per-lane (q=l31)

  auto stageK = [&](int tile, int buf) {                 // [32][32 slots] swz
    char* Kd = (char*)smem + buf * 16384;
    const unsigned short* Ks = Kg + (size_t)tile * 32 * 256;
    #pragma unroll
    for (int i = 0; i < 4; ++i) {
      int u = i * 256 + t;
      int mm = u >> 5, j = u & 31;
      const unsigned short* src = Ks + mm * 256 + ((j ^ mm) * 8);  // pre-swz
      char* dst = Kd + (i * 256 + w * 64) * 16;                    // linear
      __builtin_amdgcn_global_load_lds(
          (const __attribute__((address_space(1))) u32*)src,
          (__attribute__((address_space(3))) u32*)dst, 16, 0, 0);
    }
  };
  auto stageV = [&](int tile, int buf) {                 // [ko=4][d=256][8]
    char* Vd = (char*)smem + 32768 + buf * 16384;
    const unsigned short* Vs = Vg + tile * 32;
    #pragma unroll
    for (int i = 0; i < 4; ++i) {
      const unsigned short* src = Vs + (size_t)t * N_ + i * 8;
      char* dst = Vd + (i * 256 + w * 64) * 16;
      __builtin_amdgcn_global_load_lds(
          (const __attribute__((address_space(1))) u32*)src,
          (__attribute__((address_space(3))) u32*)dst, 16, 0, 0);
    }
  };

  auto qk = [&](int buf, f32x16& acc) {                  // S^T[kv][q] tile
    const char* Kd = (const char*)smem + buf * 16384;
    #pragma unroll
    for (int tt = 0; tt < 16; ++tt) {
      int slot = 2 * tt + hi;
      s8v ka = *(const s8v*)(Kd + l31 * 512 + ((slot ^ l31) * 16));
      acc = __builtin_amdgcn_mfma_f32_32x32x16_bf16(ka, qf[tt], acc, 0, 0, 0);
    }
  };

  auto smpv = [&](int it, f32x16& cur) {                 // branchless online SM + PV
    float rmax = cur[0];
    #pragma unroll
    for (int r = 1; r < 16; ++r) rmax = fmaxf(rmax, cur[r]);
    rmax = xhalf_max(rmax);
    float mn = fmaxf(m_r, rmax * sc);
    float corr = exp2f(m_r - mn);
    m_r = mn;
    float p[16];
    float rs = 0.f;
    #pragma unroll
    for (int r = 0; r < 16; ++r) {
      p[r] = exp2f(__builtin_fmaf(cur[r], sc, -mn));
      rs += p[r];
    }
    rs = xhalf_sum(rs);
    l_r = l_r * corr + rs;
    u32 wv[8];
    #pragma unroll
    for (int j = 0; j < 8; ++j) wv[j] = cvtpk(p[2 * j], p[2 * j + 1]);
    // one swap fills one pf0 word and one pf1... (pf0: kv 0..15, pf1: 16..31)
    swap32u(wv[0], wv[2]);   // -> pf0.u0, pf0.u2
    swap32u(wv[1], wv[3]);   // -> pf0.u1, pf0.u3
    swap32u(wv[4], wv[6]);   // -> pf1.u0, pf1.u2
    swap32u(wv[5], wv[7]);   // -> pf1.u1, pf1.u3
    union { u32 u[4]; s8v v; } pf0, pf1;
    pf0.u[0] = wv[0]; pf0.u[1] = wv[1]; pf0.u[2] = wv[2]; pf0.u[3] = wv[3];
    pf1.u[0] = wv[4]; pf1.u[1] = wv[5]; pf1.u[2] = wv[6]; pf1.u[3] = wv[7];
    const char* Vd = (const char*)smem + 32768 + (it & 1) * 16384;
    #pragma unroll
    for (int dc = 0; dc < 8; ++dc) {
      o_acc[dc] *= corr;
      s8v va0 = *(const s8v*)(Vd + ((hi) * 256 + dc * 32 + l31) * 16);
      o_acc[dc] = __builtin_amdgcn_mfma_f32_32x32x16_bf16(va0, pf0.v, o_acc[dc], 0, 0, 0);
      s8v va1 = *(const s8v*)(Vd + ((2 + hi) * 256 + dc * 32 + l31) * 16);
      o_acc[dc] = __builtin_amdgcn_mfma_f32_32x32x16_bf16(va1, pf1.v, o_acc[dc], 0, 0, 0);
    }
  };

  // prologue: K(0)->kb0, K(1)->kb1, V(0)->vb0; QK(0); protect kb0 before reuse
  stageK(0, 0);
  stageK(1, 1);
  stageV(0, 0);
  __syncthreads();
  f32x16 saA, saB;
  #pragma unroll
  for (int r = 0; r < 16; ++r) saA[r] = 0.f;
  qk(0, saA);
  __syncthreads();

  // body(it): stage K(it+2)->kb[it&1], V(it+1)->vb[(it+1)&1];
  //           QK(it+1)->nxt (interleaves with softmax+PV of tile it); barrier.
  auto body = [&](int it, f32x16& cur, f32x16& nxt) {
    int kt = it + 2 > 63 ? 63 : it + 2;
    stageK(kt, it & 1);
    stageV(it + 1, (it + 1) & 1);
    #pragma unroll
    for (int r = 0; r < 16; ++r) nxt[r] = 0.f;
    qk((it + 1) & 1, nxt);
    smpv(it, cur);
    __syncthreads();
  };

  for (int k2 = 0; k2 < 31; ++k2) {
    body(2 * k2, saA, saB);
    body(2 * k2 + 1, saB, saA);
  }
  body(62, saA, saB);
  smpv(63, saB);                                          // tail tile

  // epilogue: normalized bf16 partial + LSE (all per-lane scalars)
  float inv = 1.f / l_r;
  size_t rid = (size_t)b * N_ + q0 + w * 32 + l31;
  if (!hi) lse[(size_t)sl * (B_ * N_) + rid] = m_r + log2f(l_r);
  unsigned short* Od = Op + ((size_t)sl * (B_ * N_) + rid) * 256;
  #pragma unroll
  for (int dc = 0; dc < 8; ++dc) {
    #pragma unroll
    for (int rg = 0; rg < 4; ++rg) {
      int d0 = dc * 32 + 8 * rg + 4 * hi;                // 4 consecutive d
      u32 w0 = cvtpk(o_acc[dc][rg * 4 + 0] * inv, o_acc[dc][rg * 4 + 1] * inv);
      u32 w1 = cvtpk(o_acc[dc][rg * 4 + 2] * inv, o_acc[dc][rg * 4 + 3] * inv);
      u32x2 pk{w0, w1};
      *(u32x2*)(Od + d0) = pk;
    }
  }
}

// ---------------- merge the 4 KV-slice partials ------------------------------
__global__ __launch_bounds__(256) void attn_merge_kernel(
    const unsigned short* __restrict__ Op, const float* __restrict__ lse,
    unsigned short* __restrict__ Ob) {
  int gid = blockIdx.x * 256 + threadIdx.x;      // 524288 = 16384 rows x 32 chunks
  int row = gid >> 5;
  int co = (gid & 31) * 8;
  float L[4], lm = -1e30f;
  #pragma unroll
  for (int s = 0; s < 4; ++s) { L[s] = lse[s * (B_ * N_) + row]; lm = fmaxf(lm, L[s]); }
  float acc[8];
  #pragma unroll
  for (int e = 0; e < 8; ++e) acc[e] = 0.f;
  float wsum = 0.f;
  #pragma unroll
  for (int s = 0; s < 4; ++s) {
    float wg = exp2f(L[s] - lm);
    wsum += wg;
    s8v v = *(const s8v*)(Op + ((size_t)s * (B_ * N_) + row) * 256 + co);
    #pragma unroll
    for (int e = 0; e < 8; ++e) acc[e] += wg * bf2f((unsigned short)v[e]);
  }
  float inv = 1.f / wsum;
  s8v o;
  #pragma unroll
  for (int e = 0; e < 8; ++e) o[e] = (short)f2bf(acc[e] * inv);
  *(s8v*)(Ob + (size_t)row * 256 + co) = o;
}

// ---------------------------------------------------------------------------
extern "C" void kernel_launch(void* const* d_in, const int* in_sizes, int n_in,
                              void* d_out, int out_size, void* d_ws, size_t ws_size,
                              hipStream_t stream) {
  (void)in_sizes; (void)n_in; (void)out_size; (void)ws_size;
  const float* x  = (const float*)d_in[0];
  const float* gw = (const float*)d_in[1];
  const float* gb = (const float*)d_in[2];
  const float* wq = (const float*)d_in[3];
  const float* bq = (const float*)d_in[4];
  const float* wk = (const float*)d_in[5];
  const float* bk = (const float*)d_in[6];
  const float* wv = (const float*)d_in[7];
  const float* bv = (const float*)d_in[8];
  const float* wp = (const float*)d_in[9];
  const float* bp = (const float*)d_in[10];

  const size_t HS = (size_t)N_ * C_;              // per-batch elems
  char* ws = (char*)d_ws;
  unsigned short* wqb = (unsigned short*)ws;             // 512 KB
  float* meanp = (float*)(ws + 524288);
  float* rstdp = meanp + 64;
  unsigned short* h    = (unsigned short*)(ws + 525312); // 8 MB  [B][N][C]
  unsigned short* Qb   = h  + B_ * HS;                   // 8 MB  [B][N][C]
  unsigned short* Kb   = Qb + B_ * HS;                   // 8 MB  [B][N][C]
  unsigned short* Vb   = Kb + B_ * HS;                   // 8 MB  [B][C][N]
  unsigned short* Ob   = Vb + B_ * HS;                   // 8 MB  [B][N][C]
  unsigned short* Opart = Ob + B_ * HS;                  // 32 MB [4][B*N][C]
  float* lsep = (float*)(Opart + 4 * B_ * HS);           // 256 KB [4][B*N]

  cvt_w_kernel<<<1024, 256, 0, stream>>>(wq, wk, wv, wp, wqb);
  gn_stats_kernel<<<B_ * NG_, 256, 0, stream>>>(x, meanp, rstdp);
  gn_apply_kernel<<<dim3(N_ / 64, B_), 256, 0, stream>>>(x, gw, gb, meanp, rstdp, h);

  unsigned short* wkb = wqb + 65536;
  unsigned short* wvb = wkb + 65536;
  unsigned short* wpb = wvb + 65536;
  gemm_nt_kernel<0><<<dim3(N_ / 64, C_ / 64, B_), 256, 0, stream>>>(
      h, (long)HS, wqb, 0, bq, nullptr, 0, Qb, (long)HS, C_);
  gemm_nt_kernel<0><<<dim3(N_ / 64, C_ / 64, B_), 256, 0, stream>>>(
      h, (long)HS, wkb, 0, bk, nullptr, 0, Kb, (long)HS, C_);
  gemm_nt_kernel<1><<<dim3(C_ / 64, N_ / 64, B_), 256, 0, stream>>>(
      wvb, 0, h, (long)HS, bv, nullptr, 0, Vb, (long)HS, N_);

  // flash attention pass 1: pipelined swapped-QK^T 32x32, 4 KV slices
  const int attn_lds = 65536;
  hipFuncSetAttribute(reinterpret_cast<const void*>(attn_kernel),
                      hipFuncAttributeMaxDynamicSharedMemorySize, attn_lds);
  attn_kernel<<<dim3(512), 256, attn_lds, stream>>>(Qb, Kb, Vb, Opart, lsep);

  // merge 4 slices -> Ob
  attn_merge_kernel<<<(B_ * N_ * 32) / 256, 256, 0, stream>>>(Opart, lsep, Ob);

  // out[o][n] = wp . O[n][:] + bp + x
  gemm_nt_kernel<2><<<dim3(C_ / 64, N_ / 64, B_), 256, 0, stream>>>(
      wpb, 0, Ob, (long)HS, bp, x, (long)HS, d_out, (long)HS, N_);
}

// Round 9
// 355.736 us; speedup vs baseline: 1.0169x; 1.0169x over previous
//
#include <hip/hip_runtime.h>

#define B_ 2
#define C_ 256
#define N_ 8192
#define NG_ 32

typedef unsigned int u32;
using f32x4  = __attribute__((ext_vector_type(4))) float;
using f32x16 = __attribute__((ext_vector_type(16))) float;
using s8v    = __attribute__((ext_vector_type(8))) short;   // 8 x bf16
using u32x2  = __attribute__((ext_vector_type(2))) u32;

__device__ __forceinline__ unsigned short f2bf(float f) {
  unsigned u = __builtin_bit_cast(unsigned, f);
  return (unsigned short)((u + 0x7fffu + ((u >> 16) & 1u)) >> 16);
}
__device__ __forceinline__ float bf2f(unsigned short h) {
  return __builtin_bit_cast(float, (u32)h << 16);
}
// pack two f32 -> two bf16 (RTNE) in one instr  [HW-verified R8]
__device__ __forceinline__ u32 cvtpk(float lo, float hi) {
  u32 r;
  asm volatile("v_cvt_pk_bf16_f32 %0, %1, %2" : "=v"(r) : "v"(lo), "v"(hi));
  return r;
}
// v_permlane32_swap_b32: newA=[a.row0,b.row0], newB=[a.row1,b.row1]  [HW-verified R8]
__device__ __forceinline__ void swap32u(u32& a, u32& b) {
  asm volatile("v_permlane32_swap_b32 %0, %1" : "+v"(a), "+v"(b));
}
__device__ __forceinline__ float xhalf_max(float x) {
  float a = x, b = x;
  asm volatile("v_permlane32_swap_b32 %0, %1" : "+v"(a), "+v"(b));
  return fmaxf(a, b);
}
__device__ __forceinline__ float xhalf_sum(float x) {
  float a = x, b = x;
  asm volatile("v_permlane32_swap_b32 %0, %1" : "+v"(a), "+v"(b));
  return a + b;
}

// ---------------- weight fp32 -> bf16 (4 x 256x256, contiguous out) ---------
__global__ void cvt_w_kernel(const float* __restrict__ wq, const float* __restrict__ wk,
                             const float* __restrict__ wv, const float* __restrict__ wp,
                             unsigned short* __restrict__ out) {
  int i = blockIdx.x * 256 + threadIdx.x;        // 262144 total
  int m = i >> 16;
  const float* src = m == 0 ? wq : m == 1 ? wk : m == 2 ? wv : wp;
  out[i] = f2bf(src[i & 65535]);
}

// ---------------- groupnorm pass 1: mean/rstd per (b, group) ----------------
__global__ void gn_stats_kernel(const float* __restrict__ x,
                                float* __restrict__ mean, float* __restrict__ rstd) {
  int bg = blockIdx.x;                                  // 64 groups total
  const f32x4* p = (const f32x4*)(x + (size_t)bg * (8 * N_));
  float s = 0.f, sq = 0.f;
  for (int i = threadIdx.x; i < 8 * N_ / 4; i += 256) {
    f32x4 v = p[i];
    s  += v.x + v.y + v.z + v.w;
    sq += v.x * v.x + v.y * v.y + v.z * v.z + v.w * v.w;
  }
  #pragma unroll
  for (int o = 32; o; o >>= 1) { s += __shfl_down(s, o); sq += __shfl_down(sq, o); }
  __shared__ float ls[4], lq[4];
  int w = threadIdx.x >> 6;
  if ((threadIdx.x & 63) == 0) { ls[w] = s; lq[w] = sq; }
  __syncthreads();
  if (threadIdx.x == 0) {
    s = ls[0] + ls[1] + ls[2] + ls[3];
    sq = lq[0] + lq[1] + lq[2] + lq[3];
    float m = s / (8.f * N_);
    float var = sq / (8.f * N_) - m * m;
    mean[bg] = m;
    rstd[bg] = rsqrtf(var + 1e-5f);
  }
}

// -------- groupnorm pass 2: normalize + transpose -> h[N][C] bf16 -----------
__global__ __launch_bounds__(256) void gn_apply_kernel(
    const float* __restrict__ x, const float* __restrict__ gw, const float* __restrict__ gb,
    const float* __restrict__ mean, const float* __restrict__ rstd,
    unsigned short* __restrict__ h) {
  __shared__ unsigned short lds[256][72];
  int b = blockIdx.y, n0 = blockIdx.x * 64;
  const float* xb = x + (size_t)b * C_ * N_;
  int col = threadIdx.x & 63;
  int c0  = threadIdx.x >> 6;
  for (int r = 0; r < 64; ++r) {
    int c = r * 4 + c0;
    float v = xb[(size_t)c * N_ + n0 + col];
    int g = b * NG_ + (c >> 3);
    lds[c][col] = f2bf((v - mean[g]) * rstd[g] * gw[c] + gb[c]);
  }
  __syncthreads();
  int nl = threadIdx.x >> 2;                      // 0..63
  int cb = threadIdx.x & 3;                       // 0..3 (64-channel chunk)
  unsigned short* dst = h + ((size_t)b * N_ + n0 + nl) * C_ + cb * 64;
  #pragma unroll
  for (int g2 = 0; g2 < 8; ++g2) {
    s8v v;
    #pragma unroll
    for (int e = 0; e < 8; ++e) v[e] = (short)lds[cb * 64 + g2 * 8 + e][nl];
    *(s8v*)(dst + g2 * 8) = v;
  }
}

// -------- fused QKV projection: one pass over h, 3 weight matrices ----------
// Q[n][o], K[n][o] via mfma(a_h, b_w); V[o][n] via swapped mfma(b_w, a_h) so
// the transposed write stays lane-coalesced. bias over o in all three.
__global__ __launch_bounds__(256) void gemm_qkv_kernel(
    const unsigned short* __restrict__ h, const unsigned short* __restrict__ wqkv,
    const float* __restrict__ bq, const float* __restrict__ bk, const float* __restrict__ bv,
    unsigned short* __restrict__ Qo, unsigned short* __restrict__ Ko,
    unsigned short* __restrict__ Vo) {
  const size_t HS = (size_t)N_ * C_;
  int b = blockIdx.y;
  int i0 = blockIdx.x * 64;
  int lane = threadIdx.x & 63, w = threadIdx.x >> 6;
  int l15 = lane & 15, lg = lane >> 4;
  const unsigned short* Ap = h + (size_t)b * HS + (size_t)(i0 + w * 16 + l15) * 256 + lg * 8;
  s8v a[8];
  #pragma unroll
  for (int kt = 0; kt < 8; ++kt) a[kt] = *(const s8v*)(Ap + kt * 32);

  #pragma unroll
  for (int m = 0; m < 3; ++m) {
    const unsigned short* W = wqkv + m * 65536;
    const float* bias = m == 0 ? bq : m == 1 ? bk : bv;
    #pragma unroll
    for (int jb = 0; jb < 4; ++jb) {
      int j0 = jb * 64;
      f32x4 acc[4];
      #pragma unroll
      for (int jt = 0; jt < 4; ++jt) acc[jt] = f32x4{0.f, 0.f, 0.f, 0.f};
      #pragma unroll
      for (int kt = 0; kt < 8; ++kt) {
        #pragma unroll
        for (int jt = 0; jt < 4; ++jt) {
          s8v bb = *(const s8v*)(W + (size_t)(j0 + jt * 16 + l15) * 256 + kt * 32 + lg * 8);
          if (m < 2)
            acc[jt] = __builtin_amdgcn_mfma_f32_16x16x32_bf16(a[kt], bb, acc[jt], 0, 0, 0);
          else
            acc[jt] = __builtin_amdgcn_mfma_f32_16x16x32_bf16(bb, a[kt], acc[jt], 0, 0, 0);
        }
      }
      if (m < 2) {
        unsigned short* o = (m == 0 ? Qo : Ko) + (size_t)b * HS;
        int rowb = i0 + w * 16 + lg * 4;
        #pragma unroll
        for (int jt = 0; jt < 4; ++jt) {
          int j = j0 + jt * 16 + l15;
          float bj = bias[j];
          #pragma unroll
          for (int r = 0; r < 4; ++r)
            o[(size_t)(rowb + r) * C_ + j] = f2bf(acc[jt][r] + bj);
        }
      } else {
        unsigned short* o = Vo + (size_t)b * HS;
        int nn = i0 + w * 16 + l15;                      // col = n (coalesced)
        #pragma unroll
        for (int jt = 0; jt < 4; ++jt) {
          #pragma unroll
          for (int r = 0; r < 4; ++r) {
            int oc = j0 + jt * 16 + lg * 4 + r;          // row = out channel
            o[(size_t)oc * N_ + nn] = f2bf(acc[jt][r] + bias[oc]);
          }
        }
      }
    }
  }
}

// -------- generic C[i][j] = sum_k A[i][k]*B[j][k] (final projection) --------
__global__ __launch_bounds__(256) void gemm_out_kernel(
    const unsigned short* __restrict__ A,
    const unsigned short* __restrict__ Bm, long sB,
    const float* __restrict__ bias,
    const float* __restrict__ resid, long sR,
    float* __restrict__ outv, long sO, int ldo) {
  int b = blockIdx.z;
  const unsigned short* Bb = Bm + (size_t)b * sB;
  int i0 = blockIdx.x * 64, j0 = blockIdx.y * 64;
  int lane = threadIdx.x & 63, w = threadIdx.x >> 6;
  int l15 = lane & 15, lg = lane >> 4;
  const unsigned short* Ap = A + (size_t)(i0 + w * 16 + l15) * 256 + lg * 8;
  const unsigned short* Bp = Bb + (size_t)(j0 + l15) * 256 + lg * 8;
  f32x4 acc[4];
  #pragma unroll
  for (int jt = 0; jt < 4; ++jt) acc[jt] = f32x4{0.f, 0.f, 0.f, 0.f};
  #pragma unroll
  for (int kt = 0; kt < 8; ++kt) {
    s8v a = *(const s8v*)(Ap + kt * 32);
    #pragma unroll
    for (int jt = 0; jt < 4; ++jt) {
      s8v bb = *(const s8v*)(Bp + (size_t)jt * 16 * 256 + kt * 32);
      acc[jt] = __builtin_amdgcn_mfma_f32_16x16x32_bf16(a, bb, acc[jt], 0, 0, 0);
    }
  }
  int rowb = i0 + w * 16 + lg * 4;
  float* o = outv + (size_t)b * sO;
  const float* xr = resid + (size_t)b * sR;
  #pragma unroll
  for (int jt = 0; jt < 4; ++jt) {
    int j = j0 + jt * 16 + l15;
    #pragma unroll
    for (int r = 0; r < 4; ++r) {
      size_t idx = (size_t)(rowb + r) * ldo + j;
      o[idx] = acc[jt][r] + bias[rowb + r] + xr[idx];
    }
  }
}

// ---------------- flash attention pass 1 (swapped-QK^T, 32x32 MFMA) ---------
// 256 thr = 4 waves, 32 q-rows/wave (QBLK=128). KVBLK=32, 4 KV slices.
// R7 structure + (a) QK split into two MFMA dependency chains (s0/s1, merged
// by 16 adds; s1 dies at merge so peak liveness stays under the 2-wave cap),
// (b) T12 primitives: cvt_pk pack, permlane32_swap for the cross-half
// exchange and reduces (no ds_bpermute on the critical path).
// LDS: K 2x16KB + V 2x16KB = 65536 B. 2 blocks/CU, 2 waves/SIMD (reg-capped).
__global__ __launch_bounds__(256, 2) void attn_kernel(
    const unsigned short* __restrict__ Q, const unsigned short* __restrict__ K,
    const unsigned short* __restrict__ V, unsigned short* __restrict__ Op,
    float* __restrict__ lse) {
  extern __shared__ unsigned short smem[];
  // dispatch remap: 8 consecutive blockIdx -> 8 XCDs; each XCD's resident set
  // shares one (sl,b) so its 2MB K/V slice lives in its 4MB L2.
  int f = blockIdx.x;
  int grp = f & 7, qb = f >> 3;
  int sl = grp & 3, b = grp >> 2;
  int q0 = qb * 128;
  int kvbase = sl * 2048;
  int t = threadIdx.x, lane = t & 63, w = t >> 6;
  int l31 = lane & 31, hi = lane >> 5;

  const unsigned short* Qg = Q + ((size_t)b * N_ + q0 + w * 32 + l31) * 256;
  const unsigned short* Kg = K + ((size_t)b * N_ + kvbase) * 256;
  const unsigned short* Vg = V + (size_t)b * 256 * N_ + kvbase;
  const float sc = 0.0625f * 1.44269504088896f;          // C^-0.5 * log2(e)

  // Q as B-operand frags: col(q)=lane&31, k = hi*8+e ; 16 k-slots of 16
  s8v qf[16];
  #pragma unroll
  for (int tt = 0; tt < 16; ++tt)
    qf[tt] = *(const s8v*)(Qg + tt * 16 + hi * 8);

  f32x16 o_acc[8];                                       // O^T: d-chunk x 16
  #pragma unroll
  for (int dc = 0; dc < 8; ++dc)
    #pragma unroll
    for (int r = 0; r < 16; ++r) o_acc[dc][r] = 0.f;
  float m_r = -1e30f, l_r = 0.f;                          // per-lane (q=l31)

  auto stage = [&](int it, int bufsel) {
    char* Kd = (char*)smem + bufsel * 16384;
    char* Vd = (char*)smem + 32768 + bufsel * 16384;
    const unsigned short* Ks = Kg + (size_t)it * 32 * 256;
    const unsigned short* Vs = Vg + it * 32;
    #pragma unroll
    for (int i = 0; i < 4; ++i) {                        // K: row mm, slot j
      int u = i * 256 + t;
      int mm = u >> 5, j = u & 31;
      const unsigned short* src = Ks + mm * 256 + ((j ^ mm) * 8);  // pre-swz
      char* dst = Kd + (i * 256 + w * 64) * 16;                    // linear
      __builtin_amdgcn_global_load_lds(
          (const __attribute__((address_space(1))) u32*)src,
          (__attribute__((address_space(3))) u32*)dst, 16, 0, 0);
    }
    #pragma unroll
    for (int i = 0; i < 4; ++i) {                        // V: [ko=i][d=t][8]
      const unsigned short* src = Vs + (size_t)t * N_ + i * 8;
      char* dst = Vd + (i * 256 + w * 64) * 16;
      __builtin_amdgcn_global_load_lds(
          (const __attribute__((address_space(1))) u32*)src,
          (__attribute__((address_space(3))) u32*)dst, 16, 0, 0);
    }
  };

  stage(0, 0);
  __syncthreads();

  for (int it = 0; it < 64; ++it) {
    int cur = it & 1;
    if (it + 1 < 64) stage(it + 1, cur ^ 1);             // prefetch other buf
    const char* Kd = (const char*)smem + cur * 16384;
    const char* Vd = (const char*)smem + 32768 + cur * 16384;

    // S^T[kv][q]: two independent MFMA chains (halved dependency latency)
    f32x16 s0, s1;
    #pragma unroll
    for (int r = 0; r < 16; ++r) { s0[r] = 0.f; s1[r] = 0.f; }
    __builtin_amdgcn_s_setprio(1);
    #pragma unroll
    for (int tt = 0; tt < 16; tt += 2) {
      int slot0 = 2 * tt + hi;
      s8v ka0 = *(const s8v*)(Kd + l31 * 512 + ((slot0 ^ l31) * 16));
      s0 = __builtin_amdgcn_mfma_f32_32x32x16_bf16(ka0, qf[tt], s0, 0, 0, 0);
      int slot1 = 2 * (tt + 1) + hi;
      s8v ka1 = *(const s8v*)(Kd + l31 * 512 + ((slot1 ^ l31) * 16));
      s1 = __builtin_amdgcn_mfma_f32_32x32x16_bf16(ka1, qf[tt + 1], s1, 0, 0, 0);
    }
    __builtin_amdgcn_s_setprio(0);
    #pragma unroll
    for (int r = 0; r < 16; ++r) s0[r] += s1[r];         // s1 dies here

    // lane-local softmax (q=l31), defer-max (T13, THR=8)
    float rmax = s0[0];
    #pragma unroll
    for (int r = 1; r < 16; ++r) rmax = fmaxf(rmax, s0[r]);
    rmax = xhalf_max(rmax);
    rmax *= sc;
    if (!__all(rmax <= m_r + 8.f)) {
      float mn = fmaxf(m_r, rmax);
      float corr = exp2f(m_r - mn);
      m_r = mn;
      l_r *= corr;
      #pragma unroll
      for (int dc = 0; dc < 8; ++dc)
        #pragma unroll
        for (int r = 0; r < 16; ++r) o_acc[dc][r] *= corr;
    }
    // exp + pack pairwise (transient p), accumulate row-sum
    float rs = 0.f;
    u32 wv[8];
    #pragma unroll
    for (int j = 0; j < 8; ++j) {
      float p0 = exp2f(__builtin_fmaf(s0[2 * j],     sc, -m_r));
      float p1 = exp2f(__builtin_fmaf(s0[2 * j + 1], sc, -m_r));
      rs += p0 + p1;
      wv[j] = cvtpk(p0, p1);
    }
    l_r += xhalf_sum(rs);

    // cross-half exchange -> PV B-frags (pf0: kv 0..15, pf1: kv 16..31)
    swap32u(wv[0], wv[2]);
    swap32u(wv[1], wv[3]);
    swap32u(wv[4], wv[6]);
    swap32u(wv[5], wv[7]);
    union { u32 u[4]; s8v v; } pf0, pf1;
    pf0.u[0] = wv[0]; pf0.u[1] = wv[1]; pf0.u[2] = wv[2]; pf0.u[3] = wv[3];
    pf1.u[0] = wv[4]; pf1.u[1] = wv[5]; pf1.u[2] = wv[6]; pf1.u[3] = wv[7];

    // O^T[d][q] += sum_kv V^T[d][kv] P[q][kv]
    __builtin_amdgcn_s_setprio(1);
    #pragma unroll
    for (int dc = 0; dc < 8; ++dc) {
      s8v va0 = *(const s8v*)(Vd + ((hi) * 256 + dc * 32 + l31) * 16);
      o_acc[dc] = __builtin_amdgcn_mfma_f32_32x32x16_bf16(va0, pf0.v, o_acc[dc], 0, 0, 0);
      s8v va1 = *(const s8v*)(Vd + ((2 + hi) * 256 + dc * 32 + l31) * 16);
      o_acc[dc] = __builtin_amdgcn_mfma_f32_32x32x16_bf16(va1, pf1.v, o_acc[dc], 0, 0, 0);
    }
    __builtin_amdgcn_s_setprio(0);
    __syncthreads();
  }

  // epilogue: normalized bf16 partial + LSE (all per-lane scalars)
  float inv = 1.f / l_r;
  size_t rid = (size_t)b * N_ + q0 + w * 32 + l31;
  if (!hi) lse[(size_t)sl * (B_ * N_) + rid] = m_r + log2f(l_r);
  unsigned short* Od = Op + ((size_t)sl * (B_ * N_) + rid) * 256;
  #pragma unroll
  for (int dc = 0; dc < 8; ++dc) {
    #pragma unroll
    for (int rg = 0; rg < 4; ++rg) {
      int d0 = dc * 32 + 8 * rg + 4 * hi;                // 4 consecutive d
      u32 w0 = cvtpk(o_acc[dc][rg * 4 + 0] * inv, o_acc[dc][rg * 4 + 1] * inv);
      u32 w1 = cvtpk(o_acc[dc][rg * 4 + 2] * inv, o_acc[dc][rg * 4 + 3] * inv);
      u32x2 pk{w0, w1};
      *(u32x2*)(Od + d0) = pk;
    }
  }
}

// ---------------- merge the 4 KV-slice partials ------------------------------
__global__ __launch_bounds__(256) void attn_merge_kernel(
    const unsigned short* __restrict__ Op, const float* __restrict__ lse,
    unsigned short* __restrict__ Ob) {
  int gid = blockIdx.x * 256 + threadIdx.x;      // 524288 = 16384 rows x 32 chunks
  int row = gid >> 5;
  int co = (gid & 31) * 8;
  float L[4], lm = -1e30f;
  #pragma unroll
  for (int s = 0; s < 4; ++s) { L[s] = lse[s * (B_ * N_) + row]; lm = fmaxf(lm, L[s]); }
  float acc[8];
  #pragma unroll
  for (int e = 0; e < 8; ++e) acc[e] = 0.f;
  float wsum = 0.f;
  #pragma unroll
  for (int s = 0; s < 4; ++s) {
    float wg = exp2f(L[s] - lm);
    wsum += wg;
    s8v v = *(const s8v*)(Op + ((size_t)s * (B_ * N_) + row) * 256 + co);
    #pragma unroll
    for (int e = 0; e < 8; ++e) acc[e] += wg * bf2f((unsigned short)v[e]);
  }
  float inv = 1.f / wsum;
  s8v o;
  #pragma unroll
  for (int e = 0; e < 8; ++e) o[e] = (short)f2bf(acc[e] * inv);
  *(s8v*)(Ob + (size_t)row * 256 + co) = o;
}

// ---------------------------------------------------------------------------
extern "C" void kernel_launch(void* const* d_in, const int* in_sizes, int n_in,
                              void* d_out, int out_size, void* d_ws, size_t ws_size,
                              hipStream_t stream) {
  (void)in_sizes; (void)n_in; (void)out_size; (void)ws_size;
  const float* x  = (const float*)d_in[0];
  const float* gw = (const float*)d_in[1];
  const float* gb = (const float*)d_in[2];
  const float* wq = (const float*)d_in[3];
  const float* bq = (const float*)d_in[4];
  const float* wk = (const float*)d_in[5];
  const float* bk = (const float*)d_in[6];
  const float* wv = (const float*)d_in[7];
  const float* bv = (const float*)d_in[8];
  const float* wp = (const float*)d_in[9];
  const float* bp = (const float*)d_in[10];

  const size_t HS = (size_t)N_ * C_;              // per-batch elems
  char* ws = (char*)d_ws;
  unsigned short* wqb = (unsigned short*)ws;             // 512 KB [wq|wk|wv|wp]
  float* meanp = (float*)(ws + 524288);
  float* rstdp = meanp + 64;
  unsigned short* h    = (unsigned short*)(ws + 525312); // 8 MB  [B][N][C]
  unsigned short* Qb   = h  + B_ * HS;                   // 8 MB  [B][N][C]
  unsigned short* Kb   = Qb + B_ * HS;                   // 8 MB  [B][N][C]
  unsigned short* Vb   = Kb + B_ * HS;                   // 8 MB  [B][C][N]
  unsigned short* Ob   = Vb + B_ * HS;                   // 8 MB  [B][N][C]
  unsigned short* Opart = Ob + B_ * HS;                  // 32 MB [4][B*N][C]
  float* lsep = (float*)(Opart + 4 * B_ * HS);           // 256 KB [4][B*N]

  cvt_w_kernel<<<1024, 256, 0, stream>>>(wq, wk, wv, wp, wqb);
  gn_stats_kernel<<<B_ * NG_, 256, 0, stream>>>(x, meanp, rstdp);
  gn_apply_kernel<<<dim3(N_ / 64, B_), 256, 0, stream>>>(x, gw, gb, meanp, rstdp, h);

  unsigned short* wpb = wqb + 3 * 65536;
  // fused Q/K/V projection (reads h once)
  gemm_qkv_kernel<<<dim3(N_ / 64, B_), 256, 0, stream>>>(
      h, wqb, bq, bk, bv, Qb, Kb, Vb);

  // flash attention pass 1: swapped-QK^T 32x32, split QK chains, T12 prims
  const int attn_lds = 65536;
  hipFuncSetAttribute(reinterpret_cast<const void*>(attn_kernel),
                      hipFuncAttributeMaxDynamicSharedMemorySize, attn_lds);
  attn_kernel<<<dim3(512), 256, attn_lds, stream>>>(Qb, Kb, Vb, Opart, lsep);

  // merge 4 slices -> Ob
  attn_merge_kernel<<<(B_ * N_ * 32) / 256, 256, 0, stream>>>(Opart, lsep, Ob);

  // out[o][n] = wp . O[n][:] + bp + x
  gemm_out_kernel<<<dim3(C_ / 64, N_ / 64, B_), 256, 0, stream>>>(
      wpb, Ob, (long)HS, bp, x, (long)HS, (float*)d_out, (long)HS, N_);
}

// Round 10
// 306.369 us; speedup vs baseline: 1.1808x; 1.1611x over previous
//
#include <hip/hip_runtime.h>

#define B_ 2
#define C_ 256
#define N_ 8192
#define NG_ 32

typedef unsigned int u32;
using f32x4  = __attribute__((ext_vector_type(4))) float;
using f32x16 = __attribute__((ext_vector_type(16))) float;
using s8v    = __attribute__((ext_vector_type(8))) short;   // 8 x bf16
using u32x2  = __attribute__((ext_vector_type(2))) u32;

__device__ __forceinline__ unsigned short f2bf(float f) {
  unsigned u = __builtin_bit_cast(unsigned, f);
  return (unsigned short)((u + 0x7fffu + ((u >> 16) & 1u)) >> 16);
}
__device__ __forceinline__ float bf2f(unsigned short h) {
  return __builtin_bit_cast(float, (u32)h << 16);
}
// pack two f32 -> two bf16 (RTNE) in one instr  [HW-verified R8/R9]
__device__ __forceinline__ u32 cvtpk(float lo, float hi) {
  u32 r;
  asm("v_cvt_pk_bf16_f32 %0, %1, %2" : "=v"(r) : "v"(lo), "v"(hi));
  return r;
}
// v_permlane32_swap_b32: newA=[a.row0,b.row0], newB=[a.row1,b.row1]  [HW-verified R8/R9]
__device__ __forceinline__ void swap32u(u32& a, u32& b) {
  asm("v_permlane32_swap_b32 %0, %1" : "+v"(a), "+v"(b));
}
__device__ __forceinline__ float xhalf_max(float x) {
  float a = x, b = x;
  asm("v_permlane32_swap_b32 %0, %1" : "+v"(a), "+v"(b));
  return fmaxf(a, b);
}
__device__ __forceinline__ float xhalf_sum(float x) {
  float a = x, b = x;
  asm("v_permlane32_swap_b32 %0, %1" : "+v"(a), "+v"(b));
  return a + b;
}

// ---------------- weight fp32 -> bf16 (4 x 256x256, contiguous out) ---------
__global__ void cvt_w_kernel(const float* __restrict__ wq, const float* __restrict__ wk,
                             const float* __restrict__ wv, const float* __restrict__ wp,
                             unsigned short* __restrict__ out) {
  int i = blockIdx.x * 256 + threadIdx.x;        // 262144 total
  int m = i >> 16;
  const float* src = m == 0 ? wq : m == 1 ? wk : m == 2 ? wv : wp;
  out[i] = f2bf(src[i & 65535]);
}

// ---------------- groupnorm pass 1: mean/rstd per (b, group) ----------------
__global__ void gn_stats_kernel(const float* __restrict__ x,
                                float* __restrict__ mean, float* __restrict__ rstd) {
  int bg = blockIdx.x;                                  // 64 groups total
  const f32x4* p = (const f32x4*)(x + (size_t)bg * (8 * N_));
  float s = 0.f, sq = 0.f;
  for (int i = threadIdx.x; i < 8 * N_ / 4; i += 256) {
    f32x4 v = p[i];
    s  += v.x + v.y + v.z + v.w;
    sq += v.x * v.x + v.y * v.y + v.z * v.z + v.w * v.w;
  }
  #pragma unroll
  for (int o = 32; o; o >>= 1) { s += __shfl_down(s, o); sq += __shfl_down(sq, o); }
  __shared__ float ls[4], lq[4];
  int w = threadIdx.x >> 6;
  if ((threadIdx.x & 63) == 0) { ls[w] = s; lq[w] = sq; }
  __syncthreads();
  if (threadIdx.x == 0) {
    s = ls[0] + ls[1] + ls[2] + ls[3];
    sq = lq[0] + lq[1] + lq[2] + lq[3];
    float m = s / (8.f * N_);
    float var = sq / (8.f * N_) - m * m;
    mean[bg] = m;
    rstd[bg] = rsqrtf(var + 1e-5f);
  }
}

// -------- groupnorm pass 2: normalize + transpose -> h[N][C] bf16 -----------
__global__ __launch_bounds__(256) void gn_apply_kernel(
    const float* __restrict__ x, const float* __restrict__ gw, const float* __restrict__ gb,
    const float* __restrict__ mean, const float* __restrict__ rstd,
    unsigned short* __restrict__ h) {
  __shared__ unsigned short lds[256][72];
  int b = blockIdx.y, n0 = blockIdx.x * 64;
  const float* xb = x + (size_t)b * C_ * N_;
  int col = threadIdx.x & 63;
  int c0  = threadIdx.x >> 6;
  for (int r = 0; r < 64; ++r) {
    int c = r * 4 + c0;
    float v = xb[(size_t)c * N_ + n0 + col];
    int g = b * NG_ + (c >> 3);
    lds[c][col] = f2bf((v - mean[g]) * rstd[g] * gw[c] + gb[c]);
  }
  __syncthreads();
  int nl = threadIdx.x >> 2;                      // 0..63
  int cb = threadIdx.x & 3;                       // 0..3 (64-channel chunk)
  unsigned short* dst = h + ((size_t)b * N_ + n0 + nl) * C_ + cb * 64;
  #pragma unroll
  for (int g2 = 0; g2 < 8; ++g2) {
    s8v v;
    #pragma unroll
    for (int e = 0; e < 8; ++e) v[e] = (short)lds[cb * 64 + g2 * 8 + e][nl];
    *(s8v*)(dst + g2 * 8) = v;
  }
}

// -------- fused QKV projection: one pass over h, 3 weight matrices ----------
__global__ __launch_bounds__(256) void gemm_qkv_kernel(
    const unsigned short* __restrict__ h, const unsigned short* __restrict__ wqkv,
    const float* __restrict__ bq, const float* __restrict__ bk, const float* __restrict__ bv,
    unsigned short* __restrict__ Qo, unsigned short* __restrict__ Ko,
    unsigned short* __restrict__ Vo) {
  const size_t HS = (size_t)N_ * C_;
  int b = blockIdx.y;
  int i0 = blockIdx.x * 64;
  int lane = threadIdx.x & 63, w = threadIdx.x >> 6;
  int l15 = lane & 15, lg = lane >> 4;
  const unsigned short* Ap = h + (size_t)b * HS + (size_t)(i0 + w * 16 + l15) * 256 + lg * 8;
  s8v a[8];
  #pragma unroll
  for (int kt = 0; kt < 8; ++kt) a[kt] = *(const s8v*)(Ap + kt * 32);

  #pragma unroll
  for (int m = 0; m < 3; ++m) {
    const unsigned short* W = wqkv + m * 65536;
    const float* bias = m == 0 ? bq : m == 1 ? bk : bv;
    #pragma unroll
    for (int jb = 0; jb < 4; ++jb) {
      int j0 = jb * 64;
      f32x4 acc[4];
      #pragma unroll
      for (int jt = 0; jt < 4; ++jt) acc[jt] = f32x4{0.f, 0.f, 0.f, 0.f};
      #pragma unroll
      for (int kt = 0; kt < 8; ++kt) {
        #pragma unroll
        for (int jt = 0; jt < 4; ++jt) {
          s8v bb = *(const s8v*)(W + (size_t)(j0 + jt * 16 + l15) * 256 + kt * 32 + lg * 8);
          if (m < 2)
            acc[jt] = __builtin_amdgcn_mfma_f32_16x16x32_bf16(a[kt], bb, acc[jt], 0, 0, 0);
          else
            acc[jt] = __builtin_amdgcn_mfma_f32_16x16x32_bf16(bb, a[kt], acc[jt], 0, 0, 0);
        }
      }
      if (m < 2) {
        unsigned short* o = (m == 0 ? Qo : Ko) + (size_t)b * HS;
        int rowb = i0 + w * 16 + lg * 4;
        #pragma unroll
        for (int jt = 0; jt < 4; ++jt) {
          int j = j0 + jt * 16 + l15;
          float bj = bias[j];
          #pragma unroll
          for (int r = 0; r < 4; ++r)
            o[(size_t)(rowb + r) * C_ + j] = f2bf(acc[jt][r] + bj);
        }
      } else {
        unsigned short* o = Vo + (size_t)b * HS;
        int nn = i0 + w * 16 + l15;                      // col = n (coalesced)
        #pragma unroll
        for (int jt = 0; jt < 4; ++jt) {
          #pragma unroll
          for (int r = 0; r < 4; ++r) {
            int oc = j0 + jt * 16 + lg * 4 + r;          // row = out channel
            o[(size_t)oc * N_ + nn] = f2bf(acc[jt][r] + bias[oc]);
          }
        }
      }
    }
  }
}

// -------- final projection: out[o][n] = wp . O[n][:] + bp + x ---------------
__global__ __launch_bounds__(256) void gemm_out_kernel(
    const unsigned short* __restrict__ A,
    const unsigned short* __restrict__ Bm, long sB,
    const float* __restrict__ bias,
    const float* __restrict__ resid, long sR,
    float* __restrict__ outv, long sO, int ldo) {
  int b = blockIdx.z;
  const unsigned short* Bb = Bm + (size_t)b * sB;
  int i0 = blockIdx.x * 64, j0 = blockIdx.y * 64;
  int lane = threadIdx.x & 63, w = threadIdx.x >> 6;
  int l15 = lane & 15, lg = lane >> 4;
  const unsigned short* Ap = A + (size_t)(i0 + w * 16 + l15) * 256 + lg * 8;
  const unsigned short* Bp = Bb + (size_t)(j0 + l15) * 256 + lg * 8;
  f32x4 acc[4];
  #pragma unroll
  for (int jt = 0; jt < 4; ++jt) acc[jt] = f32x4{0.f, 0.f, 0.f, 0.f};
  #pragma unroll
  for (int kt = 0; kt < 8; ++kt) {
    s8v a = *(const s8v*)(Ap + kt * 32);
    #pragma unroll
    for (int jt = 0; jt < 4; ++jt) {
      s8v bb = *(const s8v*)(Bp + (size_t)jt * 16 * 256 + kt * 32);
      acc[jt] = __builtin_amdgcn_mfma_f32_16x16x32_bf16(a, bb, acc[jt], 0, 0, 0);
    }
  }
  int rowb = i0 + w * 16 + lg * 4;
  float* o = outv + (size_t)b * sO;
  const float* xr = resid + (size_t)b * sR;
  #pragma unroll
  for (int jt = 0; jt < 4; ++jt) {
    int j = j0 + jt * 16 + l15;
    #pragma unroll
    for (int r = 0; r < 4; ++r) {
      size_t idx = (size_t)(rowb + r) * ldo + j;
      o[idx] = acc[jt][r] + bias[rowb + r] + xr[idx];
    }
  }
}

// ---------------- flash attention pass 1 (swapped-QK^T, 32x32 MFMA) ---------
// R7 structure (single QK accumulator chain — MFMA acc chains pipeline at
// throughput, R9 proved splitting them only spills) + T12 primitives:
// cvt_pk pack (8 instrs vs ~64 VALU) and permlane32_swap for the cross-half
// reduces + P exchange (no ds_bpermute on the critical path; wv[8] only live,
// 8 regs FEWER than R7's wv+sw).
// LDS: K 2x16KB + V 2x16KB = 65536 B. 2 blocks/CU, 2 waves/SIMD (reg-capped).
__global__ __launch_bounds__(256, 2) void attn_kernel(
    const unsigned short* __restrict__ Q, const unsigned short* __restrict__ K,
    const unsigned short* __restrict__ V, unsigned short* __restrict__ Op,
    float* __restrict__ lse) {
  extern __shared__ unsigned short smem[];
  // dispatch remap: 8 consecutive blockIdx -> 8 XCDs; each XCD's resident set
  // shares one (sl,b) so its 2MB K/V slice lives in its 4MB L2.
  int f = blockIdx.x;
  int grp = f & 7, qb = f >> 3;
  int sl = grp & 3, b = grp >> 2;
  int q0 = qb * 128;
  int kvbase = sl * 2048;
  int t = threadIdx.x, lane = t & 63, w = t >> 6;
  int l31 = lane & 31, hi = lane >> 5;

  const unsigned short* Qg = Q + ((size_t)b * N_ + q0 + w * 32 + l31) * 256;
  const unsigned short* Kg = K + ((size_t)b * N_ + kvbase) * 256;
  const unsigned short* Vg = V + (size_t)b * 256 * N_ + kvbase;
  const float sc = 0.0625f * 1.44269504088896f;          // C^-0.5 * log2(e)

  // Q as B-operand frags: col(q)=lane&31, k = hi*8+e ; 16 k-slots of 16
  s8v qf[16];
  #pragma unroll
  for (int tt = 0; tt < 16; ++tt)
    qf[tt] = *(const s8v*)(Qg + tt * 16 + hi * 8);

  f32x16 o_acc[8];                                       // O^T: d-chunk x 16
  #pragma unroll
  for (int dc = 0; dc < 8; ++dc)
    #pragma unroll
    for (int r = 0; r < 16; ++r) o_acc[dc][r] = 0.f;
  float m_r = -1e30f, l_r = 0.f;                          // per-lane (q=l31)

  auto stage = [&](int it, int bufsel) {
    char* Kd = (char*)smem + bufsel * 16384;
    char* Vd = (char*)smem + 32768 + bufsel * 16384;
    const unsigned short* Ks = Kg + (size_t)it * 32 * 256;
    const unsigned short* Vs = Vg + it * 32;
    #pragma unroll
    for (int i = 0; i < 4; ++i) {                        // K: row mm, slot j
      int u = i * 256 + t;
      int mm = u >> 5, j = u & 31;
      const unsigned short* src = Ks + mm * 256 + ((j ^ mm) * 8);  // pre-swz
      char* dst = Kd + (i * 256 + w * 64) * 16;                    // linear
      __builtin_amdgcn_global_load_lds(
          (const __attribute__((address_space(1))) u32*)src,
          (__attribute__((address_space(3))) u32*)dst, 16, 0, 0);
    }
    #pragma unroll
    for (int i = 0; i < 4; ++i) {                        // V: [ko=i][d=t][8]
      const unsigned short* src = Vs + (size_t)t * N_ + i * 8;
      char* dst = Vd + (i * 256 + w * 64) * 16;
      __builtin_amdgcn_global_load_lds(
          (const __attribute__((address_space(1))) u32*)src,
          (__attribute__((address_space(3))) u32*)dst, 16, 0, 0);
    }
  };

  stage(0, 0);
  __syncthreads();

  for (int it = 0; it < 64; ++it) {
    int cur = it & 1;
    if (it + 1 < 64) stage(it + 1, cur ^ 1);             // prefetch other buf
    const char* Kd = (const char*)smem + cur * 16384;
    const char* Vd = (const char*)smem + 32768 + cur * 16384;

    // S^T[kv][q] = sum_c K[kv][c] Q[q][c]   (single acc chain, pipelined)
    f32x16 sa;
    #pragma unroll
    for (int r = 0; r < 16; ++r) sa[r] = 0.f;
    __builtin_amdgcn_s_setprio(1);
    #pragma unroll
    for (int tt = 0; tt < 16; ++tt) {
      int slot = 2 * tt + hi;
      s8v ka = *(const s8v*)(Kd + l31 * 512 + ((slot ^ l31) * 16));
      sa = __builtin_amdgcn_mfma_f32_32x32x16_bf16(ka, qf[tt], sa, 0, 0, 0);
    }
    __builtin_amdgcn_s_setprio(0);

    // lane-local softmax (q=l31), defer-max (T13, THR=8)
    float rmax = sa[0];
    #pragma unroll
    for (int r = 1; r < 16; ++r) rmax = fmaxf(rmax, sa[r]);
    rmax = xhalf_max(rmax);
    rmax *= sc;
    if (!__all(rmax <= m_r + 8.f)) {
      float mn = fmaxf(m_r, rmax);
      float corr = exp2f(m_r - mn);
      m_r = mn;
      l_r *= corr;
      #pragma unroll
      for (int dc = 0; dc < 8; ++dc)
        #pragma unroll
        for (int r = 0; r < 16; ++r) o_acc[dc][r] *= corr;
    }
    // exp + pack pairwise (transient p), accumulate row-sum
    float rs = 0.f;
    u32 wv[8];
    #pragma unroll
    for (int j = 0; j < 8; ++j) {
      float p0 = exp2f(__builtin_fmaf(sa[2 * j],     sc, -m_r));
      float p1 = exp2f(__builtin_fmaf(sa[2 * j + 1], sc, -m_r));
      rs += p0 + p1;
      wv[j] = cvtpk(p0, p1);
    }
    l_r += xhalf_sum(rs);

    // cross-half exchange -> PV B-frags (pf0: kv 0..15, pf1: kv 16..31)
    swap32u(wv[0], wv[2]);
    swap32u(wv[1], wv[3]);
    swap32u(wv[4], wv[6]);
    swap32u(wv[5], wv[7]);
    union { u32 u[4]; s8v v; } pf0, pf1;
    pf0.u[0] = wv[0]; pf0.u[1] = wv[1]; pf0.u[2] = wv[2]; pf0.u[3] = wv[3];
    pf1.u[0] = wv[4]; pf1.u[1] = wv[5]; pf1.u[2] = wv[6]; pf1.u[3] = wv[7];

    // O^T[d][q] += sum_kv V^T[d][kv] P[q][kv]
    __builtin_amdgcn_s_setprio(1);
    #pragma unroll
    for (int dc = 0; dc < 8; ++dc) {
      s8v va0 = *(const s8v*)(Vd + ((hi) * 256 + dc * 32 + l31) * 16);
      o_acc[dc] = __builtin_amdgcn_mfma_f32_32x32x16_bf16(va0, pf0.v, o_acc[dc], 0, 0, 0);
      s8v va1 = *(const s8v*)(Vd + ((2 + hi) * 256 + dc * 32 + l31) * 16);
      o_acc[dc] = __builtin_amdgcn_mfma_f32_32x32x16_bf16(va1, pf1.v, o_acc[dc], 0, 0, 0);
    }
    __builtin_amdgcn_s_setprio(0);
    __syncthreads();
  }

  // epilogue: normalized bf16 partial + LSE (all per-lane scalars)
  float inv = 1.f / l_r;
  size_t rid = (size_t)b * N_ + q0 + w * 32 + l31;
  if (!hi) lse[(size_t)sl * (B_ * N_) + rid] = m_r + log2f(l_r);
  unsigned short* Od = Op + ((size_t)sl * (B_ * N_) + rid) * 256;
  #pragma unroll
  for (int dc = 0; dc < 8; ++dc) {
    #pragma unroll
    for (int rg = 0; rg < 4; ++rg) {
      int d0 = dc * 32 + 8 * rg + 4 * hi;                // 4 consecutive d
      u32 w0 = cvtpk(o_acc[dc][rg * 4 + 0] * inv, o_acc[dc][rg * 4 + 1] * inv);
      u32 w1 = cvtpk(o_acc[dc][rg * 4 + 2] * inv, o_acc[dc][rg * 4 + 3] * inv);
      u32x2 pk{w0, w1};
      *(u32x2*)(Od + d0) = pk;
    }
  }
}

// ---------------- merge the 4 KV-slice partials ------------------------------
__global__ __launch_bounds__(256) void attn_merge_kernel(
    const unsigned short* __restrict__ Op, const float* __restrict__ lse,
    unsigned short* __restrict__ Ob) {
  int gid = blockIdx.x * 256 + threadIdx.x;      // 524288 = 16384 rows x 32 chunks
  int row = gid >> 5;
  int co = (gid & 31) * 8;
  float L[4], lm = -1e30f;
  #pragma unroll
  for (int s = 0; s < 4; ++s) { L[s] = lse[s * (B_ * N_) + row]; lm = fmaxf(lm, L[s]); }
  float acc[8];
  #pragma unroll
  for (int e = 0; e < 8; ++e) acc[e] = 0.f;
  float wsum = 0.f;
  #pragma unroll
  for (int s = 0; s < 4; ++s) {
    float wg = exp2f(L[s] - lm);
    wsum += wg;
    s8v v = *(const s8v*)(Op + ((size_t)s * (B_ * N_) + row) * 256 + co);
    #pragma unroll
    for (int e = 0; e < 8; ++e) acc[e] += wg * bf2f((unsigned short)v[e]);
  }
  float inv = 1.f / wsum;
  s8v o;
  #pragma unroll
  for (int e = 0; e < 8; ++e) o[e] = (short)f2bf(acc[e] * inv);
  *(s8v*)(Ob + (size_t)row * 256 + co) = o;
}

// ---------------------------------------------------------------------------
extern "C" void kernel_launch(void* const* d_in, const int* in_sizes, int n_in,
                              void* d_out, int out_size, void* d_ws, size_t ws_size,
                              hipStream_t stream) {
  (void)in_sizes; (void)n_in; (void)out_size; (void)ws_size;
  const float* x  = (const float*)d_in[0];
  const float* gw = (const float*)d_in[1];
  const float* gb = (const float*)d_in[2];
  const float* wq = (const float*)d_in[3];
  const float* bq = (const float*)d_in[4];
  const float* wk = (const float*)d_in[5];
  const float* bk = (const float*)d_in[6];
  const float* wv = (const float*)d_in[7];
  const float* bv = (const float*)d_in[8];
  const float* wp = (const float*)d_in[9];
  const float* bp = (const float*)d_in[10];

  const size_t HS = (size_t)N_ * C_;              // per-batch elems
  char* ws = (char*)d_ws;
  unsigned short* wqb = (unsigned short*)ws;             // 512 KB [wq|wk|wv|wp]
  float* meanp = (float*)(ws + 524288);
  float* rstdp = meanp + 64;
  unsigned short* h    = (unsigned short*)(ws + 525312); // 8 MB  [B][N][C]
  unsigned short* Qb   = h  + B_ * HS;                   // 8 MB  [B][N][C]
  unsigned short* Kb   = Qb + B_ * HS;                   // 8 MB  [B][N][C]
  unsigned short* Vb   = Kb + B_ * HS;                   // 8 MB  [B][C][N]
  unsigned short* Ob   = Vb + B_ * HS;                   // 8 MB  [B][N][C]
  unsigned short* Opart = Ob + B_ * HS;                  // 32 MB [4][B*N][C]
  float* lsep = (float*)(Opart + 4 * B_ * HS);           // 256 KB [4][B*N]

  cvt_w_kernel<<<1024, 256, 0, stream>>>(wq, wk, wv, wp, wqb);
  gn_stats_kernel<<<B_ * NG_, 256, 0, stream>>>(x, meanp, rstdp);
  gn_apply_kernel<<<dim3(N_ / 64, B_), 256, 0, stream>>>(x, gw, gb, meanp, rstdp, h);

  unsigned short* wpb = wqb + 3 * 65536;
  // fused Q/K/V projection (reads h once)
  gemm_qkv_kernel<<<dim3(N_ / 64, B_), 256, 0, stream>>>(
      h, wqb, bq, bk, bv, Qb, Kb, Vb);

  // flash attention pass 1: swapped-QK^T 32x32 + T12, 4 KV slices
  const int attn_lds = 65536;
  hipFuncSetAttribute(reinterpret_cast<const void*>(attn_kernel),
                      hipFuncAttributeMaxDynamicSharedMemorySize, attn_lds);
  attn_kernel<<<dim3(512), 256, attn_lds, stream>>>(Qb, Kb, Vb, Opart, lsep);

  // merge 4 slices -> Ob
  attn_merge_kernel<<<(B_ * N_ * 32) / 256, 256, 0, stream>>>(Opart, lsep, Ob);

  // out[o][n] = wp . O[n][:] + bp + x
  gemm_out_kernel<<<dim3(C_ / 64, N_ / 64, B_), 256, 0, stream>>>(
      wpb, Ob, (long)HS, bp, x, (long)HS, (float*)d_out, (long)HS, N_);
}

// Round 11
// 240.909 us; speedup vs baseline: 1.5016x; 1.2717x over previous
//
#include <hip/hip_runtime.h>

#define B_ 2
#define C_ 256
#define N_ 8192
#define NG_ 32

typedef unsigned int u32;
using f32x4  = __attribute__((ext_vector_type(4))) float;
using f32x16 = __attribute__((ext_vector_type(16))) float;
using s8v    = __attribute__((ext_vector_type(8))) short;   // 8 x bf16
using u32x2  = __attribute__((ext_vector_type(2))) u32;

__device__ __forceinline__ unsigned short f2bf(float f) {
  unsigned u = __builtin_bit_cast(unsigned, f);
  return (unsigned short)((u + 0x7fffu + ((u >> 16) & 1u)) >> 16);
}
__device__ __forceinline__ float bf2f(unsigned short h) {
  return __builtin_bit_cast(float, (u32)h << 16);
}
// pack two f32 -> two bf16 (RTNE) in one instr  [HW-verified R8/R9/R10]
__device__ __forceinline__ u32 cvtpk(float lo, float hi) {
  u32 r;
  asm("v_cvt_pk_bf16_f32 %0, %1, %2" : "=v"(r) : "v"(lo), "v"(hi));
  return r;
}
// v_permlane32_swap_b32: newA=[a.row0,b.row0], newB=[a.row1,b.row1]  [HW-verified]
__device__ __forceinline__ void swap32u(u32& a, u32& b) {
  asm("v_permlane32_swap_b32 %0, %1" : "+v"(a), "+v"(b));
}
__device__ __forceinline__ float xhalf_max(float x) {
  float a = x, b = x;
  asm("v_permlane32_swap_b32 %0, %1" : "+v"(a), "+v"(b));
  return fmaxf(a, b);
}
__device__ __forceinline__ float xhalf_sum(float x) {
  float a = x, b = x;
  asm("v_permlane32_swap_b32 %0, %1" : "+v"(a), "+v"(b));
  return a + b;
}

// ------- prep: weight fp32->bf16 (folded) + two-level GN stats partials -----
// 512 blocks x 256 thr. Block bi: converts 512 weight elems AND partial-sums
// GN slice (bg = bi>>3 over 8 channels, s = bi&7 over 1024 n).
__global__ __launch_bounds__(256) void prep_kernel(
    const float* __restrict__ x,
    const float* __restrict__ wq, const float* __restrict__ wk,
    const float* __restrict__ wv, const float* __restrict__ wp,
    unsigned short* __restrict__ wout, float* __restrict__ part) {
  int t = threadIdx.x, bi = blockIdx.x;
  // weight conversion: 2 elems/thread, 512 blocks x 256 x 2 = 262144
  int j = bi * 512 + t * 2;
  int m = j >> 16;
  const float* src = m == 0 ? wq : m == 1 ? wk : m == 2 ? wv : wp;
  int off = j & 65535;
  *(u32*)(wout + j) = cvtpk(src[off], src[off + 1]);
  // GN partial stats
  int bg = bi >> 3, s = bi & 7;
  const float* xp = x + (size_t)bg * 8 * N_ + s * 1024;
  float sm = 0.f, sq = 0.f;
  for (int i = t; i < 2048; i += 256) {          // 8 rows x 256 f32x4
    int r = i >> 8, c4 = i & 255;
    f32x4 v = *(const f32x4*)(xp + (size_t)r * N_ + c4 * 4);
    sm += v.x + v.y + v.z + v.w;
    sq += v.x * v.x + v.y * v.y + v.z * v.z + v.w * v.w;
  }
  #pragma unroll
  for (int o = 32; o; o >>= 1) { sm += __shfl_down(sm, o); sq += __shfl_down(sq, o); }
  __shared__ float ls[4], lq[4];
  int w = t >> 6;
  if ((t & 63) == 0) { ls[w] = sm; lq[w] = sq; }
  __syncthreads();
  if (t == 0) {
    part[(bg * 8 + s) * 2]     = ls[0] + ls[1] + ls[2] + ls[3];
    part[(bg * 8 + s) * 2 + 1] = lq[0] + lq[1] + lq[2] + lq[3];
  }
}

// ------- fused GN-apply + QKV projection (h never materialized) -------------
// grid (N/64, B) x 512 thr (8 waves = 2/SIMD). Phases: stats finalize ->
// per-channel scale/shift -> load x tile, normalize, pack bf16 pairs into
// LDS [256 c][38 u32] (write conflict-free, read <=2-way) -> A-frag gather ->
// 3 projections; wave w: rows (w>>1)*16, jb half (w&1).
__global__ __launch_bounds__(512) void qkv_kernel(
    const float* __restrict__ x, const float* __restrict__ gw, const float* __restrict__ gb,
    const float* __restrict__ part, const unsigned short* __restrict__ wqkv,
    const float* __restrict__ bq, const float* __restrict__ bk, const float* __restrict__ bv,
    unsigned short* __restrict__ Qo, unsigned short* __restrict__ Ko,
    unsigned short* __restrict__ Vo) {
  __shared__ u32 hx[256][38];                    // [c][n-pair] bf16x2
  __shared__ float gmean[32], grstd[32];
  __shared__ float scl[256], sft[256];
  const size_t HS = (size_t)N_ * C_;
  int b = blockIdx.y, n0 = blockIdx.x * 64;
  int t = threadIdx.x;

  if (t < 32) {                                   // finalize stats (batch b)
    float sm = 0.f, sq = 0.f;
    #pragma unroll
    for (int s = 0; s < 8; ++s) {
      sm += part[((b * 32 + t) * 8 + s) * 2];
      sq += part[((b * 32 + t) * 8 + s) * 2 + 1];
    }
    float mean = sm * (1.f / 65536.f);
    float var = sq * (1.f / 65536.f) - mean * mean;
    gmean[t] = mean;
    grstd[t] = rsqrtf(var + 1e-5f);
  }
  __syncthreads();
  if (t < 256) {                                  // per-channel scale/shift
    int g = t >> 3;
    float s0 = grstd[g] * gw[t];
    scl[t] = s0;
    sft[t] = gb[t] - gmean[g] * s0;
  }
  __syncthreads();

  {                                               // load + normalize + pack
    int col2 = (t & 31) * 2;                      // n-pair offset
    int c0 = t >> 5;                              // 0..15
    const float* xb = x + (size_t)b * C_ * N_ + n0 + col2;
    #pragma unroll
    for (int r = 0; r < 16; ++r) {
      int c = r * 16 + c0;
      const float* xp = xb + (size_t)c * N_;
      float v0 = __builtin_fmaf(xp[0], scl[c], sft[c]);
      float v1 = __builtin_fmaf(xp[1], scl[c], sft[c]);
      hx[c][t & 31] = cvtpk(v0, v1);
    }
  }
  __syncthreads();

  int lane = t & 63, w = t >> 6;
  int l15 = lane & 15, lg = lane >> 4;
  int rbase = (w >> 1) * 16 + l15;                // n-row within tile
  s8v a[8];                                        // A-frags: 8 consecutive c
  #pragma unroll
  for (int kt = 0; kt < 8; ++kt) {
    #pragma unroll
    for (int e = 0; e < 8; ++e) {
      u32 wd = hx[kt * 32 + lg * 8 + e][rbase >> 1];
      a[kt][e] = (short)(unsigned short)(wd >> ((rbase & 1) * 16));
    }
  }

  int gn = n0 + (w >> 1) * 16;                    // global n base for this wave
  int jb0 = (w & 1) * 2;
  #pragma unroll
  for (int m = 0; m < 3; ++m) {
    const unsigned short* W = wqkv + m * 65536;
    const float* bias = m == 0 ? bq : m == 1 ? bk : bv;
    #pragma unroll
    for (int jx = 0; jx < 2; ++jx) {
      int j0 = (jb0 + jx) * 64;
      f32x4 acc[4];
      #pragma unroll
      for (int jt = 0; jt < 4; ++jt) acc[jt] = f32x4{0.f, 0.f, 0.f, 0.f};
      #pragma unroll
      for (int kt = 0; kt < 8; ++kt) {
        #pragma unroll
        for (int jt = 0; jt < 4; ++jt) {
          s8v bb = *(const s8v*)(W + (size_t)(j0 + jt * 16 + l15) * 256 + kt * 32 + lg * 8);
          if (m < 2)
            acc[jt] = __builtin_amdgcn_mfma_f32_16x16x32_bf16(a[kt], bb, acc[jt], 0, 0, 0);
          else
            acc[jt] = __builtin_amdgcn_mfma_f32_16x16x32_bf16(bb, a[kt], acc[jt], 0, 0, 0);
        }
      }
      if (m < 2) {
        unsigned short* o = (m == 0 ? Qo : Ko) + (size_t)b * HS;
        int rowb = gn + lg * 4;
        #pragma unroll
        for (int jt = 0; jt < 4; ++jt) {
          int jj = j0 + jt * 16 + l15;
          float bj = bias[jj];
          #pragma unroll
          for (int r = 0; r < 4; ++r)
            o[(size_t)(rowb + r) * C_ + jj] = f2bf(acc[jt][r] + bj);
        }
      } else {
        unsigned short* o = Vo + (size_t)b * HS;
        int nn = gn + l15;                         // coalesced over n
        #pragma unroll
        for (int jt = 0; jt < 4; ++jt) {
          #pragma unroll
          for (int r = 0; r < 4; ++r) {
            int oc = j0 + jt * 16 + lg * 4 + r;
            o[(size_t)oc * N_ + nn] = f2bf(acc[jt][r] + bias[oc]);
          }
        }
      }
    }
  }
}

// -------- final projection: out[o][n] = wp . O[n][:] + bp + x ---------------
__global__ __launch_bounds__(256) void gemm_out_kernel(
    const unsigned short* __restrict__ A,
    const unsigned short* __restrict__ Bm, long sB,
    const float* __restrict__ bias,
    const float* __restrict__ resid, long sR,
    float* __restrict__ outv, long sO, int ldo) {
  int b = blockIdx.z;
  const unsigned short* Bb = Bm + (size_t)b * sB;
  int i0 = blockIdx.x * 64, j0 = blockIdx.y * 64;
  int lane = threadIdx.x & 63, w = threadIdx.x >> 6;
  int l15 = lane & 15, lg = lane >> 4;
  const unsigned short* Ap = A + (size_t)(i0 + w * 16 + l15) * 256 + lg * 8;
  const unsigned short* Bp = Bb + (size_t)(j0 + l15) * 256 + lg * 8;
  f32x4 acc[4];
  #pragma unroll
  for (int jt = 0; jt < 4; ++jt) acc[jt] = f32x4{0.f, 0.f, 0.f, 0.f};
  #pragma unroll
  for (int kt = 0; kt < 8; ++kt) {
    s8v a = *(const s8v*)(Ap + kt * 32);
    #pragma unroll
    for (int jt = 0; jt < 4; ++jt) {
      s8v bb = *(const s8v*)(Bp + (size_t)jt * 16 * 256 + kt * 32);
      acc[jt] = __builtin_amdgcn_mfma_f32_16x16x32_bf16(a, bb, acc[jt], 0, 0, 0);
    }
  }
  int rowb = i0 + w * 16 + lg * 4;
  float* o = outv + (size_t)b * sO;
  const float* xr = resid + (size_t)b * sR;
  #pragma unroll
  for (int jt = 0; jt < 4; ++jt) {
    int j = j0 + jt * 16 + l15;
    #pragma unroll
    for (int r = 0; r < 4; ++r) {
      size_t idx = (size_t)(rowb + r) * ldo + j;
      o[idx] = acc[jt][r] + bias[rowb + r] + xr[idx];
    }
  }
}

// ---------------- flash attention pass 1 (UNCHANGED from R10) ---------------
__global__ __launch_bounds__(256, 2) void attn_kernel(
    const unsigned short* __restrict__ Q, const unsigned short* __restrict__ K,
    const unsigned short* __restrict__ V, unsigned short* __restrict__ Op,
    float* __restrict__ lse) {
  extern __shared__ unsigned short smem[];
  int f = blockIdx.x;
  int grp = f & 7, qb = f >> 3;
  int sl = grp & 3, b = grp >> 2;
  int q0 = qb * 128;
  int kvbase = sl * 2048;
  int t = threadIdx.x, lane = t & 63, w = t >> 6;
  int l31 = lane & 31, hi = lane >> 5;

  const unsigned short* Qg = Q + ((size_t)b * N_ + q0 + w * 32 + l31) * 256;
  const unsigned short* Kg = K + ((size_t)b * N_ + kvbase) * 256;
  const unsigned short* Vg = V + (size_t)b * 256 * N_ + kvbase;
  const float sc = 0.0625f * 1.44269504088896f;          // C^-0.5 * log2(e)

  s8v qf[16];
  #pragma unroll
  for (int tt = 0; tt < 16; ++tt)
    qf[tt] = *(const s8v*)(Qg + tt * 16 + hi * 8);

  f32x16 o_acc[8];
  #pragma unroll
  for (int dc = 0; dc < 8; ++dc)
    #pragma unroll
    for (int r = 0; r < 16; ++r) o_acc[dc][r] = 0.f;
  float m_r = -1e30f, l_r = 0.f;

  auto stage = [&](int it, int bufsel) {
    char* Kd = (char*)smem + bufsel * 16384;
    char* Vd = (char*)smem + 32768 + bufsel * 16384;
    const unsigned short* Ks = Kg + (size_t)it * 32 * 256;
    const unsigned short* Vs = Vg + it * 32;
    #pragma unroll
    for (int i = 0; i < 4; ++i) {
      int u = i * 256 + t;
      int mm = u >> 5, j = u & 31;
      const unsigned short* src = Ks + mm * 256 + ((j ^ mm) * 8);
      char* dst = Kd + (i * 256 + w * 64) * 16;
      __builtin_amdgcn_global_load_lds(
          (const __attribute__((address_space(1))) u32*)src,
          (__attribute__((address_space(3))) u32*)dst, 16, 0, 0);
    }
    #pragma unroll
    for (int i = 0; i < 4; ++i) {
      const unsigned short* src = Vs + (size_t)t * N_ + i * 8;
      char* dst = Vd + (i * 256 + w * 64) * 16;
      __builtin_amdgcn_global_load_lds(
          (const __attribute__((address_space(1))) u32*)src,
          (__attribute__((address_space(3))) u32*)dst, 16, 0, 0);
    }
  };

  stage(0, 0);
  __syncthreads();

  for (int it = 0; it < 64; ++it) {
    int cur = it & 1;
    if (it + 1 < 64) stage(it + 1, cur ^ 1);
    const char* Kd = (const char*)smem + cur * 16384;
    const char* Vd = (const char*)smem + 32768 + cur * 16384;

    f32x16 sa;
    #pragma unroll
    for (int r = 0; r < 16; ++r) sa[r] = 0.f;
    __builtin_amdgcn_s_setprio(1);
    #pragma unroll
    for (int tt = 0; tt < 16; ++tt) {
      int slot = 2 * tt + hi;
      s8v ka = *(const s8v*)(Kd + l31 * 512 + ((slot ^ l31) * 16));
      sa = __builtin_amdgcn_mfma_f32_32x32x16_bf16(ka, qf[tt], sa, 0, 0, 0);
    }
    __builtin_amdgcn_s_setprio(0);

    float rmax = sa[0];
    #pragma unroll
    for (int r = 1; r < 16; ++r) rmax = fmaxf(rmax, sa[r]);
    rmax = xhalf_max(rmax);
    rmax *= sc;
    if (!__all(rmax <= m_r + 8.f)) {
      float mn = fmaxf(m_r, rmax);
      float corr = exp2f(m_r - mn);
      m_r = mn;
      l_r *= corr;
      #pragma unroll
      for (int dc = 0; dc < 8; ++dc)
        #pragma unroll
        for (int r = 0; r < 16; ++r) o_acc[dc][r] *= corr;
    }
    float rs = 0.f;
    u32 wv[8];
    #pragma unroll
    for (int j = 0; j < 8; ++j) {
      float p0 = exp2f(__builtin_fmaf(sa[2 * j],     sc, -m_r));
      float p1 = exp2f(__builtin_fmaf(sa[2 * j + 1], sc, -m_r));
      rs += p0 + p1;
      wv[j] = cvtpk(p0, p1);
    }
    l_r += xhalf_sum(rs);

    swap32u(wv[0], wv[2]);
    swap32u(wv[1], wv[3]);
    swap32u(wv[4], wv[6]);
    swap32u(wv[5], wv[7]);
    union { u32 u[4]; s8v v; } pf0, pf1;
    pf0.u[0] = wv[0]; pf0.u[1] = wv[1]; pf0.u[2] = wv[2]; pf0.u[3] = wv[3];
    pf1.u[0] = wv[4]; pf1.u[1] = wv[5]; pf1.u[2] = wv[6]; pf1.u[3] = wv[7];

    __builtin_amdgcn_s_setprio(1);
    #pragma unroll
    for (int dc = 0; dc < 8; ++dc) {
      s8v va0 = *(const s8v*)(Vd + ((hi) * 256 + dc * 32 + l31) * 16);
      o_acc[dc] = __builtin_amdgcn_mfma_f32_32x32x16_bf16(va0, pf0.v, o_acc[dc], 0, 0, 0);
      s8v va1 = *(const s8v*)(Vd + ((2 + hi) * 256 + dc * 32 + l31) * 16);
      o_acc[dc] = __builtin_amdgcn_mfma_f32_32x32x16_bf16(va1, pf1.v, o_acc[dc], 0, 0, 0);
    }
    __builtin_amdgcn_s_setprio(0);
    __syncthreads();
  }

  float inv = 1.f / l_r;
  size_t rid = (size_t)b * N_ + q0 + w * 32 + l31;
  if (!hi) lse[(size_t)sl * (B_ * N_) + rid] = m_r + log2f(l_r);
  unsigned short* Od = Op + ((size_t)sl * (B_ * N_) + rid) * 256;
  #pragma unroll
  for (int dc = 0; dc < 8; ++dc) {
    #pragma unroll
    for (int rg = 0; rg < 4; ++rg) {
      int d0 = dc * 32 + 8 * rg + 4 * hi;
      u32 w0 = cvtpk(o_acc[dc][rg * 4 + 0] * inv, o_acc[dc][rg * 4 + 1] * inv);
      u32 w1 = cvtpk(o_acc[dc][rg * 4 + 2] * inv, o_acc[dc][rg * 4 + 3] * inv);
      u32x2 pk{w0, w1};
      *(u32x2*)(Od + d0) = pk;
    }
  }
}

// ---------------- merge the 4 KV-slice partials ------------------------------
__global__ __launch_bounds__(256) void attn_merge_kernel(
    const unsigned short* __restrict__ Op, const float* __restrict__ lse,
    unsigned short* __restrict__ Ob) {
  int gid = blockIdx.x * 256 + threadIdx.x;      // 524288 = 16384 rows x 32 chunks
  int row = gid >> 5;
  int co = (gid & 31) * 8;
  float L[4], lm = -1e30f;
  #pragma unroll
  for (int s = 0; s < 4; ++s) { L[s] = lse[s * (B_ * N_) + row]; lm = fmaxf(lm, L[s]); }
  float acc[8];
  #pragma unroll
  for (int e = 0; e < 8; ++e) acc[e] = 0.f;
  float wsum = 0.f;
  #pragma unroll
  for (int s = 0; s < 4; ++s) {
    float wg = exp2f(L[s] - lm);
    wsum += wg;
    s8v v = *(const s8v*)(Op + ((size_t)s * (B_ * N_) + row) * 256 + co);
    #pragma unroll
    for (int e = 0; e < 8; ++e) acc[e] += wg * bf2f((unsigned short)v[e]);
  }
  float inv = 1.f / wsum;
  s8v o;
  #pragma unroll
  for (int e = 0; e < 8; ++e) o[e] = (short)f2bf(acc[e] * inv);
  *(s8v*)(Ob + (size_t)row * 256 + co) = o;
}

// ---------------------------------------------------------------------------
extern "C" void kernel_launch(void* const* d_in, const int* in_sizes, int n_in,
                              void* d_out, int out_size, void* d_ws, size_t ws_size,
                              hipStream_t stream) {
  (void)in_sizes; (void)n_in; (void)out_size; (void)ws_size;
  const float* x  = (const float*)d_in[0];
  const float* gw = (const float*)d_in[1];
  const float* gb = (const float*)d_in[2];
  const float* wq = (const float*)d_in[3];
  const float* bq = (const float*)d_in[4];
  const float* wk = (const float*)d_in[5];
  const float* bk = (const float*)d_in[6];
  const float* wv = (const float*)d_in[7];
  const float* bv = (const float*)d_in[8];
  const float* wp = (const float*)d_in[9];
  const float* bp = (const float*)d_in[10];

  const size_t HS = (size_t)N_ * C_;              // per-batch elems
  char* ws = (char*)d_ws;
  unsigned short* wqb = (unsigned short*)ws;             // 512 KB [wq|wk|wv|wp]
  float* part = (float*)(ws + 524288);                   // 4 KB [64][8][2]
  unsigned short* Qb   = (unsigned short*)(ws + 528384); // 8 MB  [B][N][C]
  unsigned short* Kb   = Qb + B_ * HS;                   // 8 MB  [B][N][C]
  unsigned short* Vb   = Kb + B_ * HS;                   // 8 MB  [B][C][N]
  unsigned short* Ob   = Vb + B_ * HS;                   // 8 MB  [B][N][C]
  unsigned short* Opart = Ob + B_ * HS;                  // 32 MB [4][B*N][C]
  float* lsep = (float*)(Opart + 4 * B_ * HS);           // 256 KB [4][B*N]

  // prep: weight cvt + GN stats partials (512 blocks, full-chip BW)
  prep_kernel<<<512, 256, 0, stream>>>(x, wq, wk, wv, wp, wqb, part);

  // fused GN-apply + QKV projection
  qkv_kernel<<<dim3(N_ / 64, B_), 512, 0, stream>>>(
      x, gw, gb, part, wqb, bq, bk, bv, Qb, Kb, Vb);

  // flash attention pass 1: swapped-QK^T 32x32 + T12, 4 KV slices
  const int attn_lds = 65536;
  hipFuncSetAttribute(reinterpret_cast<const void*>(attn_kernel),
                      hipFuncAttributeMaxDynamicSharedMemorySize, attn_lds);
  attn_kernel<<<dim3(512), 256, attn_lds, stream>>>(Qb, Kb, Vb, Opart, lsep);

  // merge 4 slices -> Ob
  attn_merge_kernel<<<(B_ * N_ * 32) / 256, 256, 0, stream>>>(Opart, lsep, Ob);

  // out[o][n] = wp . O[n][:] + bp + x
  unsigned short* wpb = wqb + 3 * 65536;
  gemm_out_kernel<<<dim3(C_ / 64, N_ / 64, B_), 256, 0, stream>>>(
      wpb, Ob, (long)HS, bp, x, (long)HS, (float*)d_out, (long)HS, N_);
}

// Round 12
// 228.948 us; speedup vs baseline: 1.5800x; 1.0522x over previous
//
#include <hip/hip_runtime.h>

#define B_ 2
#define C_ 256
#define N_ 8192
#define NG_ 32

typedef unsigned int u32;
using f32x4  = __attribute__((ext_vector_type(4))) float;
using f32x16 = __attribute__((ext_vector_type(16))) float;
using s8v    = __attribute__((ext_vector_type(8))) short;   // 8 x bf16
using u32x2  = __attribute__((ext_vector_type(2))) u32;

__device__ __forceinline__ unsigned short f2bf(float f) {
  unsigned u = __builtin_bit_cast(unsigned, f);
  return (unsigned short)((u + 0x7fffu + ((u >> 16) & 1u)) >> 16);
}
__device__ __forceinline__ float bf2f(unsigned short h) {
  return __builtin_bit_cast(float, (u32)h << 16);
}
// pack two f32 -> two bf16 (RTNE) in one instr  [HW-verified R8-R11]
__device__ __forceinline__ u32 cvtpk(float lo, float hi) {
  u32 r;
  asm("v_cvt_pk_bf16_f32 %0, %1, %2" : "=v"(r) : "v"(lo), "v"(hi));
  return r;
}
// v_permlane32_swap_b32: newA=[a.row0,b.row0], newB=[a.row1,b.row1]  [HW-verified]
__device__ __forceinline__ void swap32u(u32& a, u32& b) {
  asm("v_permlane32_swap_b32 %0, %1" : "+v"(a), "+v"(b));
}
__device__ __forceinline__ float xhalf_max(float x) {
  float a = x, b = x;
  asm("v_permlane32_swap_b32 %0, %1" : "+v"(a), "+v"(b));
  return fmaxf(a, b);
}
__device__ __forceinline__ float xhalf_sum(float x) {
  float a = x, b = x;
  asm("v_permlane32_swap_b32 %0, %1" : "+v"(a), "+v"(b));
  return a + b;
}

// ------- prep: weight fp32->bf16 (folded) + two-level GN stats partials -----
__global__ __launch_bounds__(256) void prep_kernel(
    const float* __restrict__ x,
    const float* __restrict__ wq, const float* __restrict__ wk,
    const float* __restrict__ wv, const float* __restrict__ wp,
    unsigned short* __restrict__ wout, float* __restrict__ part) {
  int t = threadIdx.x, bi = blockIdx.x;
  int j = bi * 512 + t * 2;
  int m = j >> 16;
  const float* src = m == 0 ? wq : m == 1 ? wk : m == 2 ? wv : wp;
  int off = j & 65535;
  *(u32*)(wout + j) = cvtpk(src[off], src[off + 1]);
  int bg = bi >> 3, s = bi & 7;
  const float* xp = x + (size_t)bg * 8 * N_ + s * 1024;
  float sm = 0.f, sq = 0.f;
  for (int i = t; i < 2048; i += 256) {          // 8 rows x 256 f32x4
    int r = i >> 8, c4 = i & 255;
    f32x4 v = *(const f32x4*)(xp + (size_t)r * N_ + c4 * 4);
    sm += v.x + v.y + v.z + v.w;
    sq += v.x * v.x + v.y * v.y + v.z * v.z + v.w * v.w;
  }
  #pragma unroll
  for (int o = 32; o; o >>= 1) { sm += __shfl_down(sm, o); sq += __shfl_down(sq, o); }
  __shared__ float ls[4], lq[4];
  int w = t >> 6;
  if ((t & 63) == 0) { ls[w] = sm; lq[w] = sq; }
  __syncthreads();
  if (t == 0) {
    part[(bg * 8 + s) * 2]     = ls[0] + ls[1] + ls[2] + ls[3];
    part[(bg * 8 + s) * 2 + 1] = lq[0] + lq[1] + lq[2] + lq[3];
  }
}

// ------- fused GN-apply + QKV projection (h never materialized) -------------
__global__ __launch_bounds__(512) void qkv_kernel(
    const float* __restrict__ x, const float* __restrict__ gw, const float* __restrict__ gb,
    const float* __restrict__ part, const unsigned short* __restrict__ wqkv,
    const float* __restrict__ bq, const float* __restrict__ bk, const float* __restrict__ bv,
    unsigned short* __restrict__ Qo, unsigned short* __restrict__ Ko,
    unsigned short* __restrict__ Vo) {
  __shared__ u32 hx[256][38];                    // [c][n-pair] bf16x2
  __shared__ float gmean[32], grstd[32];
  __shared__ float scl[256], sft[256];
  const size_t HS = (size_t)N_ * C_;
  int b = blockIdx.y, n0 = blockIdx.x * 64;
  int t = threadIdx.x;

  if (t < 32) {
    float sm = 0.f, sq = 0.f;
    #pragma unroll
    for (int s = 0; s < 8; ++s) {
      sm += part[((b * 32 + t) * 8 + s) * 2];
      sq += part[((b * 32 + t) * 8 + s) * 2 + 1];
    }
    float mean = sm * (1.f / 65536.f);
    float var = sq * (1.f / 65536.f) - mean * mean;
    gmean[t] = mean;
    grstd[t] = rsqrtf(var + 1e-5f);
  }
  __syncthreads();
  if (t < 256) {
    int g = t >> 3;
    float s0 = grstd[g] * gw[t];
    scl[t] = s0;
    sft[t] = gb[t] - gmean[g] * s0;
  }
  __syncthreads();

  {
    int col2 = (t & 31) * 2;
    int c0 = t >> 5;
    const float* xb = x + (size_t)b * C_ * N_ + n0 + col2;
    #pragma unroll
    for (int r = 0; r < 16; ++r) {
      int c = r * 16 + c0;
      const float* xp = xb + (size_t)c * N_;
      float v0 = __builtin_fmaf(xp[0], scl[c], sft[c]);
      float v1 = __builtin_fmaf(xp[1], scl[c], sft[c]);
      hx[c][t & 31] = cvtpk(v0, v1);
    }
  }
  __syncthreads();

  int lane = t & 63, w = t >> 6;
  int l15 = lane & 15, lg = lane >> 4;
  int rbase = (w >> 1) * 16 + l15;
  s8v a[8];
  #pragma unroll
  for (int kt = 0; kt < 8; ++kt) {
    #pragma unroll
    for (int e = 0; e < 8; ++e) {
      u32 wd = hx[kt * 32 + lg * 8 + e][rbase >> 1];
      a[kt][e] = (short)(unsigned short)(wd >> ((rbase & 1) * 16));
    }
  }

  int gn = n0 + (w >> 1) * 16;
  int jb0 = (w & 1) * 2;
  #pragma unroll
  for (int m = 0; m < 3; ++m) {
    const unsigned short* W = wqkv + m * 65536;
    const float* bias = m == 0 ? bq : m == 1 ? bk : bv;
    #pragma unroll
    for (int jx = 0; jx < 2; ++jx) {
      int j0 = (jb0 + jx) * 64;
      f32x4 acc[4];
      #pragma unroll
      for (int jt = 0; jt < 4; ++jt) acc[jt] = f32x4{0.f, 0.f, 0.f, 0.f};
      #pragma unroll
      for (int kt = 0; kt < 8; ++kt) {
        #pragma unroll
        for (int jt = 0; jt < 4; ++jt) {
          s8v bb = *(const s8v*)(W + (size_t)(j0 + jt * 16 + l15) * 256 + kt * 32 + lg * 8);
          if (m < 2)
            acc[jt] = __builtin_amdgcn_mfma_f32_16x16x32_bf16(a[kt], bb, acc[jt], 0, 0, 0);
          else
            acc[jt] = __builtin_amdgcn_mfma_f32_16x16x32_bf16(bb, a[kt], acc[jt], 0, 0, 0);
        }
      }
      if (m < 2) {
        unsigned short* o = (m == 0 ? Qo : Ko) + (size_t)b * HS;
        int rowb = gn + lg * 4;
        #pragma unroll
        for (int jt = 0; jt < 4; ++jt) {
          int jj = j0 + jt * 16 + l15;
          float bj = bias[jj];
          #pragma unroll
          for (int r = 0; r < 4; ++r)
            o[(size_t)(rowb + r) * C_ + jj] = f2bf(acc[jt][r] + bj);
        }
      } else {
        unsigned short* o = Vo + (size_t)b * HS;
        int nn = gn + l15;
        #pragma unroll
        for (int jt = 0; jt < 4; ++jt) {
          #pragma unroll
          for (int r = 0; r < 4; ++r) {
            int oc = j0 + jt * 16 + lg * 4 + r;
            o[(size_t)oc * N_ + nn] = f2bf(acc[jt][r] + bias[oc]);
          }
        }
      }
    }
  }
}

// ---------------- flash attention pass 1 (UNCHANGED from R10/R11) -----------
__global__ __launch_bounds__(256, 2) void attn_kernel(
    const unsigned short* __restrict__ Q, const unsigned short* __restrict__ K,
    const unsigned short* __restrict__ V, unsigned short* __restrict__ Op,
    float* __restrict__ lse) {
  extern __shared__ unsigned short smem[];
  int f = blockIdx.x;
  int grp = f & 7, qb = f >> 3;
  int sl = grp & 3, b = grp >> 2;
  int q0 = qb * 128;
  int kvbase = sl * 2048;
  int t = threadIdx.x, lane = t & 63, w = t >> 6;
  int l31 = lane & 31, hi = lane >> 5;

  const unsigned short* Qg = Q + ((size_t)b * N_ + q0 + w * 32 + l31) * 256;
  const unsigned short* Kg = K + ((size_t)b * N_ + kvbase) * 256;
  const unsigned short* Vg = V + (size_t)b * 256 * N_ + kvbase;
  const float sc = 0.0625f * 1.44269504088896f;          // C^-0.5 * log2(e)

  s8v qf[16];
  #pragma unroll
  for (int tt = 0; tt < 16; ++tt)
    qf[tt] = *(const s8v*)(Qg + tt * 16 + hi * 8);

  f32x16 o_acc[8];
  #pragma unroll
  for (int dc = 0; dc < 8; ++dc)
    #pragma unroll
    for (int r = 0; r < 16; ++r) o_acc[dc][r] = 0.f;
  float m_r = -1e30f, l_r = 0.f;

  auto stage = [&](int it, int bufsel) {
    char* Kd = (char*)smem + bufsel * 16384;
    char* Vd = (char*)smem + 32768 + bufsel * 16384;
    const unsigned short* Ks = Kg + (size_t)it * 32 * 256;
    const unsigned short* Vs = Vg + it * 32;
    #pragma unroll
    for (int i = 0; i < 4; ++i) {
      int u = i * 256 + t;
      int mm = u >> 5, j = u & 31;
      const unsigned short* src = Ks + mm * 256 + ((j ^ mm) * 8);
      char* dst = Kd + (i * 256 + w * 64) * 16;
      __builtin_amdgcn_global_load_lds(
          (const __attribute__((address_space(1))) u32*)src,
          (__attribute__((address_space(3))) u32*)dst, 16, 0, 0);
    }
    #pragma unroll
    for (int i = 0; i < 4; ++i) {
      const unsigned short* src = Vs + (size_t)t * N_ + i * 8;
      char* dst = Vd + (i * 256 + w * 64) * 16;
      __builtin_amdgcn_global_load_lds(
          (const __attribute__((address_space(1))) u32*)src,
          (__attribute__((address_space(3))) u32*)dst, 16, 0, 0);
    }
  };

  stage(0, 0);
  __syncthreads();

  for (int it = 0; it < 64; ++it) {
    int cur = it & 1;
    if (it + 1 < 64) stage(it + 1, cur ^ 1);
    const char* Kd = (const char*)smem + cur * 16384;
    const char* Vd = (const char*)smem + 32768 + cur * 16384;

    f32x16 sa;
    #pragma unroll
    for (int r = 0; r < 16; ++r) sa[r] = 0.f;
    __builtin_amdgcn_s_setprio(1);
    #pragma unroll
    for (int tt = 0; tt < 16; ++tt) {
      int slot = 2 * tt + hi;
      s8v ka = *(const s8v*)(Kd + l31 * 512 + ((slot ^ l31) * 16));
      sa = __builtin_amdgcn_mfma_f32_32x32x16_bf16(ka, qf[tt], sa, 0, 0, 0);
    }
    __builtin_amdgcn_s_setprio(0);

    float rmax = sa[0];
    #pragma unroll
    for (int r = 1; r < 16; ++r) rmax = fmaxf(rmax, sa[r]);
    rmax = xhalf_max(rmax);
    rmax *= sc;
    if (!__all(rmax <= m_r + 8.f)) {
      float mn = fmaxf(m_r, rmax);
      float corr = exp2f(m_r - mn);
      m_r = mn;
      l_r *= corr;
      #pragma unroll
      for (int dc = 0; dc < 8; ++dc)
        #pragma unroll
        for (int r = 0; r < 16; ++r) o_acc[dc][r] *= corr;
    }
    float rs = 0.f;
    u32 wv[8];
    #pragma unroll
    for (int j = 0; j < 8; ++j) {
      float p0 = exp2f(__builtin_fmaf(sa[2 * j],     sc, -m_r));
      float p1 = exp2f(__builtin_fmaf(sa[2 * j + 1], sc, -m_r));
      rs += p0 + p1;
      wv[j] = cvtpk(p0, p1);
    }
    l_r += xhalf_sum(rs);

    swap32u(wv[0], wv[2]);
    swap32u(wv[1], wv[3]);
    swap32u(wv[4], wv[6]);
    swap32u(wv[5], wv[7]);
    union { u32 u[4]; s8v v; } pf0, pf1;
    pf0.u[0] = wv[0]; pf0.u[1] = wv[1]; pf0.u[2] = wv[2]; pf0.u[3] = wv[3];
    pf1.u[0] = wv[4]; pf1.u[1] = wv[5]; pf1.u[2] = wv[6]; pf1.u[3] = wv[7];

    __builtin_amdgcn_s_setprio(1);
    #pragma unroll
    for (int dc = 0; dc < 8; ++dc) {
      s8v va0 = *(const s8v*)(Vd + ((hi) * 256 + dc * 32 + l31) * 16);
      o_acc[dc] = __builtin_amdgcn_mfma_f32_32x32x16_bf16(va0, pf0.v, o_acc[dc], 0, 0, 0);
      s8v va1 = *(const s8v*)(Vd + ((2 + hi) * 256 + dc * 32 + l31) * 16);
      o_acc[dc] = __builtin_amdgcn_mfma_f32_32x32x16_bf16(va1, pf1.v, o_acc[dc], 0, 0, 0);
    }
    __builtin_amdgcn_s_setprio(0);
    __syncthreads();
  }

  float inv = 1.f / l_r;
  size_t rid = (size_t)b * N_ + q0 + w * 32 + l31;
  if (!hi) lse[(size_t)sl * (B_ * N_) + rid] = m_r + log2f(l_r);
  unsigned short* Od = Op + ((size_t)sl * (B_ * N_) + rid) * 256;
  #pragma unroll
  for (int dc = 0; dc < 8; ++dc) {
    #pragma unroll
    for (int rg = 0; rg < 4; ++rg) {
      int d0 = dc * 32 + 8 * rg + 4 * hi;
      u32 w0 = cvtpk(o_acc[dc][rg * 4 + 0] * inv, o_acc[dc][rg * 4 + 1] * inv);
      u32 w1 = cvtpk(o_acc[dc][rg * 4 + 2] * inv, o_acc[dc][rg * 4 + 3] * inv);
      u32x2 pk{w0, w1};
      *(u32x2*)(Od + d0) = pk;
    }
  }
}

// ------- fused merge + output projection: out = wp . mergedO + bp + x -------
// grid (N/32, B) x 256 thr (4 waves). Phase 1: merge 4 KV-slice partials
// in-register -> LDS [32 n][32 slot][8 c], slot^=row XOR (write & read at the
// b128 conflict-free minimum). Phase 2: out[c][n] = sum_k wp[c][k] O[n][k],
// A=wp from L2, B from LDS; epilogue + bias + fp32 residual. Ob eliminated.
__global__ __launch_bounds__(256) void out_kernel(
    const unsigned short* __restrict__ Op, const float* __restrict__ lse,
    const unsigned short* __restrict__ W, const float* __restrict__ bias,
    const float* __restrict__ x, float* __restrict__ out) {
  __shared__ unsigned short hx[32][32][8];       // 16 KB
  int b = blockIdx.y, n0 = blockIdx.x * 32;
  int t = threadIdx.x;

  // ---- merge phase ----
  int row = t >> 3;                               // 0..31
  int ch8 = t & 7;                                // 0..7
  size_t rid = (size_t)b * N_ + n0 + row;
  float L[4], lm = -1e30f;
  #pragma unroll
  for (int s = 0; s < 4; ++s) {
    L[s] = lse[(size_t)s * (B_ * N_) + rid];
    lm = fmaxf(lm, L[s]);
  }
  float wg[4], wsum = 0.f;
  #pragma unroll
  for (int s = 0; s < 4; ++s) { wg[s] = exp2f(L[s] - lm); wsum += wg[s]; }
  float inv = 1.f / wsum;
  #pragma unroll
  for (int s = 0; s < 4; ++s) wg[s] *= inv;
  #pragma unroll
  for (int cb = 0; cb < 4; ++cb) {
    int chunk = cb * 8 + ch8;                     // 0..31
    float acc[8];
    #pragma unroll
    for (int e = 0; e < 8; ++e) acc[e] = 0.f;
    #pragma unroll
    for (int s = 0; s < 4; ++s) {
      s8v v = *(const s8v*)(Op + ((size_t)s * (B_ * N_) + rid) * 256 + chunk * 8);
      #pragma unroll
      for (int e = 0; e < 8; ++e)
        acc[e] = __builtin_fmaf(wg[s], bf2f((unsigned short)v[e]), acc[e]);
    }
    union { u32 u[4]; s8v v; } pk;
    pk.u[0] = cvtpk(acc[0], acc[1]);
    pk.u[1] = cvtpk(acc[2], acc[3]);
    pk.u[2] = cvtpk(acc[4], acc[5]);
    pk.u[3] = cvtpk(acc[6], acc[7]);
    *(s8v*)&hx[row][chunk ^ row][0] = pk.v;       // XOR swizzle
  }
  __syncthreads();

  // ---- GEMM phase: wave w owns channels w*64..w*64+63 ----
  int lane = t & 63, w = t >> 6;
  int l15 = lane & 15, lg = lane >> 4;
  f32x4 acc[4][2];
  #pragma unroll
  for (int ct = 0; ct < 4; ++ct)
    #pragma unroll
    for (int jt = 0; jt < 2; ++jt) acc[ct][jt] = f32x4{0.f, 0.f, 0.f, 0.f};
  #pragma unroll
  for (int kt = 0; kt < 8; ++kt) {
    s8v bb[2];
    #pragma unroll
    for (int jt = 0; jt < 2; ++jt) {
      int n = jt * 16 + l15;
      bb[jt] = *(const s8v*)&hx[n][(kt * 4 + lg) ^ n][0];
    }
    #pragma unroll
    for (int ct = 0; ct < 4; ++ct) {
      s8v aa = *(const s8v*)(W + (size_t)(w * 64 + ct * 16 + l15) * 256 + kt * 32 + lg * 8);
      #pragma unroll
      for (int jt = 0; jt < 2; ++jt)
        acc[ct][jt] = __builtin_amdgcn_mfma_f32_16x16x32_bf16(aa, bb[jt], acc[ct][jt], 0, 0, 0);
    }
  }
  // epilogue: out[b][c][n] = acc + bias[c] + x[b][c][n]
  #pragma unroll
  for (int ct = 0; ct < 4; ++ct) {
    #pragma unroll
    for (int r = 0; r < 4; ++r) {
      int c = w * 64 + ct * 16 + lg * 4 + r;
      float bc = bias[c];
      size_t base = ((size_t)b * C_ + c) * N_ + n0;
      #pragma unroll
      for (int jt = 0; jt < 2; ++jt) {
        int n = jt * 16 + l15;
        out[base + n] = acc[ct][jt][r] + bc + x[base + n];
      }
    }
  }
}

// ---------------------------------------------------------------------------
extern "C" void kernel_launch(void* const* d_in, const int* in_sizes, int n_in,
                              void* d_out, int out_size, void* d_ws, size_t ws_size,
                              hipStream_t stream) {
  (void)in_sizes; (void)n_in; (void)out_size; (void)ws_size;
  const float* x  = (const float*)d_in[0];
  const float* gw = (const float*)d_in[1];
  const float* gb = (const float*)d_in[2];
  const float* wq = (const float*)d_in[3];
  const float* bq = (const float*)d_in[4];
  const float* wk = (const float*)d_in[5];
  const float* bk = (const float*)d_in[6];
  const float* wv = (const float*)d_in[7];
  const float* bv = (const float*)d_in[8];
  const float* wp = (const float*)d_in[9];
  const float* bp = (const float*)d_in[10];

  const size_t HS = (size_t)N_ * C_;              // per-batch elems
  char* ws = (char*)d_ws;
  unsigned short* wqb = (unsigned short*)ws;             // 512 KB [wq|wk|wv|wp]
  float* part = (float*)(ws + 524288);                   // 4 KB [64][8][2]
  unsigned short* Qb   = (unsigned short*)(ws + 528384); // 8 MB  [B][N][C]
  unsigned short* Kb   = Qb + B_ * HS;                   // 8 MB  [B][N][C]
  unsigned short* Vb   = Kb + B_ * HS;                   // 8 MB  [B][C][N]
  unsigned short* Opart = Vb + B_ * HS;                  // 32 MB [4][B*N][C]
  float* lsep = (float*)(Opart + 4 * B_ * HS);           // 256 KB [4][B*N]

  // prep: weight cvt + GN stats partials (512 blocks, full-chip BW)
  prep_kernel<<<512, 256, 0, stream>>>(x, wq, wk, wv, wp, wqb, part);

  // fused GN-apply + QKV projection
  qkv_kernel<<<dim3(N_ / 64, B_), 512, 0, stream>>>(
      x, gw, gb, part, wqb, bq, bk, bv, Qb, Kb, Vb);

  // flash attention pass 1: swapped-QK^T 32x32 + T12, 4 KV slices
  const int attn_lds = 65536;
  hipFuncSetAttribute(reinterpret_cast<const void*>(attn_kernel),
                      hipFuncAttributeMaxDynamicSharedMemorySize, attn_lds);
  attn_kernel<<<dim3(512), 256, attn_lds, stream>>>(Qb, Kb, Vb, Opart, lsep);

  // fused merge + output projection + residual
  unsigned short* wpb = wqb + 3 * 65536;
  out_kernel<<<dim3(N_ / 32, B_), 256, 0, stream>>>(
      Opart, lsep, wpb, bp, x, (float*)d_out);
}